// Round 13
// baseline (211.328 us; speedup 1.0000x reference)
//
#include <hip/hip_runtime.h>
#include <hip/hip_bf16.h>

typedef unsigned int  u32;
typedef unsigned short u16;
typedef __attribute__((ext_vector_type(8))) short bf16x8;
typedef __attribute__((ext_vector_type(4))) float f32x4;
typedef __attribute__((ext_vector_type(4))) u32 u32x4;

#define NPIX 65536

// ---------------- ws byte offsets ----------------
constexpr size_t SIG   = 0;
constexpr size_t B1OFF = 256;
constexpr size_t B2OFF = B1OFF + 2048;
constexpr size_t WC1   = B2OFF + 1024;        // 128x576 bf16
constexpr size_t WC2   = WC1 + 147456;        // 64x1152
constexpr size_t WF1   = WC2 + 147456;        // 128x1152
constexpr size_t WF2   = WF1 + 294912;        // 64x1152
constexpr size_t WP1   = WF2 + 147456;        // 512x64
constexpr size_t WP2   = WP1 + 65536;         // 256x128
constexpr size_t XB    = WP2 + 65536;         // 65536x64 bf16
constexpr size_t HBUF  = XB + 8388608;        // 65536x128 bf16
constexpr size_t QKVS2 = HBUF + 16777216;     // 65536x256 bf16
constexpr size_t XC    = QKVS2 + 33554432;    // 65536x128 bf16 concat
constexpr size_t QKVS1 = XC + 16777216;       // 65536x512 bf16
constexpr size_t Y1    = QKVS1;
constexpr size_t TBUF  = QKVS1 + 16777216;
constexpr size_t GRAM  = QKVS1 + 67108864;

// ---------------- helpers ----------------
__device__ __forceinline__ float gelu_f(float v) {
    float xa = fabsf(v) * 0.70710678118654752f;
    float t  = __fdividef(1.0f, fmaf(0.3275911f, xa, 1.0f));
    float poly = t * fmaf(t, fmaf(t, fmaf(t, fmaf(t, 1.061405429f, -1.453152027f),
                   1.421413741f), -0.284496736f), 0.254829592f);
    float erfv = 1.0f - poly * __expf(-xa * xa);
    erfv = copysignf(erfv, v);
    return 0.5f * v * (1.0f + erfv);
}
__device__ __forceinline__ u16 f2bf(float f) {
    __hip_bfloat16 b = __float2bfloat16(f);
    return *reinterpret_cast<u16*>(&b);
}
__device__ __forceinline__ float blo(u32 u) {
    union { u32 i; float f; } x; x.i = u << 16; return x.f;
}
__device__ __forceinline__ float bhi(u32 u) {
    union { u32 i; float f; } x; x.i = u & 0xffff0000u; return x.f;
}
__device__ __forceinline__ u32 packbf(float a, float b) {
    return (u32)f2bf(a) | ((u32)f2bf(b) << 16);
}
__device__ __forceinline__ void g2l16(const void* g, void* l) {
    __builtin_amdgcn_global_load_lds(
        (const __attribute__((address_space(1))) u32*)g,
        (__attribute__((address_space(3))) u32*)l, 16, 0, 0);
}
template<int N>
__device__ __forceinline__ void waitvm() {
    asm volatile("s_waitcnt vmcnt(%0)" :: "n"(N) : "memory");
}

// ---------------- block reduction ----------------
__device__ float block_sum(float vv, float* red) {
    #pragma unroll
    for (int m = 1; m < 64; m <<= 1) vv += __shfl_xor(vv, m);
    int tid = threadIdx.x;
    __syncthreads();
    if ((tid & 63) == 0) red[tid >> 6] = vv;
    __syncthreads();
    return red[0] + red[1] + red[2] + red[3];
}

// ---------------- Gram matrix ----------------
__global__ __launch_bounds__(256)
void gram_kernel(const float* __restrict__ cW1, const float* __restrict__ cW2,
                 const float* __restrict__ fW1, const float* __restrict__ fW2,
                 float* __restrict__ Gall) {
    int bid = blockIdx.x;
    const float* W; int O, K, wsel, tile;
    if (bid < 64)       { W = cW1; O = 128; K = 576;  wsel = 0; tile = bid; }
    else if (bid < 80)  { W = cW2; O = 64;  K = 1152; wsel = 1; tile = bid - 64; }
    else if (bid < 144) { W = fW1; O = 128; K = 1152; wsel = 2; tile = bid - 80; }
    else                { W = fW2; O = 64;  K = 1152; wsel = 3; tile = bid - 144; }
    int ntiles = O >> 4;
    int ti0 = (tile / ntiles) << 4, tj0 = (tile % ntiles) << 4;
    __shared__ float Wi[16][33], Wj[16][33];
    int tid = threadIdx.x;
    int ti = tid >> 4, tj = tid & 15;
    int r = tid >> 5, c = tid & 31;
    float acc = 0.f;
    for (int k0 = 0; k0 < K; k0 += 32) {
        Wi[r][c]     = W[(size_t)(ti0 + r) * K + k0 + c];
        Wi[r + 8][c] = W[(size_t)(ti0 + r + 8) * K + k0 + c];
        Wj[r][c]     = W[(size_t)(tj0 + r) * K + k0 + c];
        Wj[r + 8][c] = W[(size_t)(tj0 + r + 8) * K + k0 + c];
        __syncthreads();
        #pragma unroll
        for (int k = 0; k < 32; ++k)
            acc += Wi[ti][k] * Wj[tj][k];
        __syncthreads();
    }
    Gall[wsel * 16384 + (ti0 + ti) * 128 + (tj0 + tj)] = acc;
}

// ---------------- power iteration ----------------
__global__ __launch_bounds__(256)
void power_kernel(const float* __restrict__ Gall, float* __restrict__ sig) {
    int wsel = blockIdx.x;
    const float* G = Gall + wsel * 16384;
    const int O = (wsel == 0 || wsel == 2) ? 128 : 64;
    __shared__ float u[128], t[128], red[4];
    int tid = threadIdx.x;
    if (tid < O) u[tid] = 1.0f / sqrtf((float)O);
    __syncthreads();
    for (int it = 0; it < 3; ++it) {
        if (tid < O) {
            float s = 0.f;
            const float4* gr = reinterpret_cast<const float4*>(G + (size_t)tid * 128);
            for (int j = 0; j < O / 4; ++j) {
                float4 g = gr[j];
                s += g.x * u[4*j] + g.y * u[4*j+1] + g.z * u[4*j+2] + g.w * u[4*j+3];
            }
            t[tid] = s;
        }
        __syncthreads();
        float loc = (tid < O) ? t[tid] * t[tid] : 0.f;
        float nt = sqrtf(block_sum(loc, red));
        if (it == 2) {
            float locd = (tid < O) ? u[tid] * t[tid] : 0.f;
            float dot = block_sum(locd, red);
            if (tid == 0) sig[wsel] = nt / sqrtf(dot + 1e-24f);
        } else {
            if (tid < O) u[tid] = t[tid] / (nt + 1e-12f);
            __syncthreads();
        }
    }
}

// ---------------- conv weight prep: [O][C][3][3]/sigma -> bf16 [O][tap*C+ci] ----------------
__global__ __launch_bounds__(256)
void prep_conv_w(const float* __restrict__ cW1, const float* __restrict__ cW2,
                 const float* __restrict__ fW1, const float* __restrict__ fW2,
                 const float* __restrict__ sig,
                 u16* wc1, u16* wc2, u16* wf1, u16* wf2) {
    int wsel = blockIdx.y;
    const float* src; u16* dst; int O, C;
    switch (wsel) {
        case 0:  src = cW1; dst = wc1; O = 128; C = 64;  break;
        case 1:  src = cW2; dst = wc2; O = 64;  C = 128; break;
        case 2:  src = fW1; dst = wf1; O = 128; C = 128; break;
        default: src = fW2; dst = wf2; O = 64;  C = 128; break;
    }
    int idx = blockIdx.x * 256 + threadIdx.x;
    if (idx >= O * C * 9) return;
    int o = idx / (C * 9);
    int rem = idx - o * (C * 9);
    int ci = rem / 9, tap = rem - ci * 9;
    float v = src[idx] / sig[wsel];
    dst[(size_t)o * (C * 9) + tap * C + ci] = f2bf(v);
}

// ---------------- projection weight/bias prep ----------------
__global__ __launch_bounds__(256)
void prep_proj(const float* q1W, const float* k1W, const float* v1W, const float* s1W,
               const float* q2W, const float* k2W, const float* v2W, const float* s2W,
               const float* q1b, const float* k1b, const float* v1b, const float* s1b,
               const float* q2b, const float* k2b, const float* v2b, const float* s2b,
               u16* wp1, u16* wp2, float* b1, float* b2) {
    const float* W1[4] = {q1W, k1W, v1W, s1W};
    const float* W2[4] = {q2W, k2W, v2W, s2W};
    const float* Bb1[4] = {q1b, k1b, v1b, s1b};
    const float* Bb2[4] = {q2b, k2b, v2b, s2b};
    int idx = blockIdx.x * 256 + threadIdx.x;
    if (idx < 32768) {
        int w = idx >> 13, r = idx & 8191;
        wp1[(size_t)w * 8192 + r] = f2bf(W1[w][r]);
    } else if (idx < 65536) {
        int j = idx - 32768; int w = j >> 13, r = j & 8191;
        wp2[(size_t)w * 8192 + r] = f2bf(W2[w][r]);
    } else if (idx < 66048) {
        int j = idx - 65536; int w = j >> 7; b1[j] = Bb1[w][j & 127];
    } else if (idx < 66304) {
        int j = idx - 66048; int w = j >> 6; b2[j] = Bb2[w][j & 63];
    }
}

// ---------------- x NCHW f32 -> [pix][64] bf16 ----------------
__global__ __launch_bounds__(256)
void convert_x(const float* __restrict__ x, u16* __restrict__ xb) {
    __shared__ float tile[64][65];
    int b = blockIdx.x >> 6, y = blockIdx.x & 63;
    int tid = threadIdx.x;
    #pragma unroll
    for (int i = 0; i < 16; ++i) {
        int c = (tid >> 6) + i * 4;
        tile[c][tid & 63] = x[(((size_t)b * 64 + c) << 12) + (y << 6) + (tid & 63)];
    }
    __syncthreads();
    #pragma unroll
    for (int i = 0; i < 16; ++i) {
        int idx = tid + i * 256;
        int p = idx >> 6, c = idx & 63;
        xb[(((size_t)b << 12) + (y << 6) + p) * 64 + c] = f2bf(tile[c][p]);
    }
}

// ---------------- direct conv: A-halo (staged once/ch-half) + ring-3 B ----------------
// Block = 4 image rows x 64 cols (256 pixels), 512 threads / 8 waves (wm=row,
// wn=ch-half-of-BN). Per ch-half: stage 6x72 halo ONCE (55KB), then 9 taps,
// each staging only the 16KB B tap-slice (ring-3, counted vmcnt - never 0
// mid-loop). Staged bytes/block: 400KB per 256 px vs 1152KB for im2col GEMM
// (the measured per-CU staging-BW law). MFMA/block (7.7us conv3) >> staging
// (~3us) so 8 waves hide the 1-block/CU latency. Grid = 256 = 1 block/CU.
template<int CCF, int NHALF, int BN, int OUTM>
__global__ __launch_bounds__(512)
void conv_kernel(const u16* __restrict__ A, const u16* __restrict__ Bw,
                 const float* __restrict__ bias, void* __restrict__ Cout,
                 int ostride, int ocol0, int do_gelu) {
    constexpr int KFULL = CCF * 9;
    constexpr int NF = BN / 32;           // B frags per wave (wave covers BN/2)
    constexpr int HB = BN / 2;
    constexpr int LPS = BN / 64;          // B loads / thread / stage
    constexpr int W = 72;                 // halo width (66 used, padded to 9x8)
    constexpr int NLR = 9;                // 8-col wave-loads per halo row
    __shared__ u16 Ah[6 * W * 64];        // 55.3KB ch-half halo
    __shared__ u16 Bls[3][BN * 64];       // ring-3 B tap slices

    const int tid = threadIdx.x;
    const int w = tid >> 6;
    const int lane = tid & 63;
    const int wm = w >> 1, wn = w & 1;
    const int img = blockIdx.x >> 4;
    const int y0 = (blockIdx.x & 15) << 2;
    const int lr = lane & 15, lg = lane >> 4;

    const int cg8 = (((tid & 7) ^ ((tid >> 3) & 7)) << 3);
    const int brow = tid >> 3;            // B staging row (0..63) per sweep

    // hoisted swizzled B ds_read offsets
    int offB[2][NF];
    #pragma unroll
    for (int ks = 0; ks < 2; ++ks)
        #pragma unroll
        for (int nf = 0; nf < NF; ++nf) {
            int Rb = wn * HB + nf * 16 + lr;
            int cl = ks * 4 + lg;
            offB[ks][nf] = Rb * 64 + ((cl ^ (Rb & 7)) << 3);
        }

    f32x4 acc[4][NF];
    #pragma unroll
    for (int i = 0; i < 4; ++i)
        #pragma unroll
        for (int j = 0; j < NF; ++j) {
            f32x4 z = {0.f, 0.f, 0.f, 0.f};
            acc[i][j] = z;
        }

    for (int h = 0; h < NHALF; ++h) {
        __syncthreads();                  // prev halo/B readers done
        // ---- stage A halo for ch-half h (once) ----
        {
            const int cch = lane & 7;
            const int cof = lane >> 3;
            for (int L = w; L < 6 * NLR; L += 8) {
                int row = L / NLR, cb = (L - row * NLR) * 8;
                int c = cb + cof;
                int yy = min(max(y0 + row - 1, 0), 63);
                int xx = min(max(c - 1, 0), 63);
                const u16* g = A + (size_t)((img << 12) + (yy << 6) + xx) * CCF
                                 + h * 64 + ((cch ^ (c & 7)) << 3);
                g2l16(g, &Ah[(row * W + cb) * 64]);
            }
        }
        // ---- B tap staging (ring-3) ----
        auto stageB = [&](int t) {
            const int buf = t % 3;
            #pragma unroll
            for (int i = 0; i < LPS; ++i) {
                const u16* g = Bw + (size_t)(brow + i * 64) * KFULL
                                 + t * CCF + h * 64 + cg8;
                g2l16(g, &Bls[buf][(i * 64 + (w << 3)) * 64]);
            }
        };
        stageB(0);
        stageB(1);
        waitvm<LPS>();                    // halo + B0 landed; B1 in flight
        __builtin_amdgcn_s_barrier();
        __builtin_amdgcn_sched_barrier(0);

        #pragma unroll
        for (int t = 0; t < 9; ++t) {
            if (t + 2 < 9) stageB(t + 2); // buf (t+2)%3: readers cleared at t-1
            __builtin_amdgcn_sched_barrier(0);
            const int dy = t / 3 - 1, dx = t % 3 - 1;
            const u16* Bb = &Bls[t % 3][0];
            #pragma unroll
            for (int ks = 0; ks < 2; ++ks) {
                bf16x8 af[4];
                #pragma unroll
                for (int mf = 0; mf < 4; ++mf) {
                    int col = mf * 16 + lr + dx + 1;
                    int addr = ((wm + dy + 1) * W + col) * 64
                             + (((ks * 4 + lg) ^ (col & 7)) << 3);
                    af[mf] = *reinterpret_cast<const bf16x8*>(&Ah[addr]);
                }
                #pragma unroll
                for (int nf = 0; nf < NF; ++nf) {
                    bf16x8 bv = *reinterpret_cast<const bf16x8*>(Bb + offB[ks][nf]);
                    #pragma unroll
                    for (int mf = 0; mf < 4; ++mf)
                        acc[mf][nf] = __builtin_amdgcn_mfma_f32_16x16x32_bf16(
                            af[mf], bv, acc[mf][nf], 0, 0, 0);
                }
            }
            __builtin_amdgcn_sched_barrier(0);
            if (t < 8) {
                if (t + 2 < 9) waitvm<LPS>();   // B(t+1) landed; B(t+2) flying
                else           waitvm<0>();     // tail: drain B(8)
                __builtin_amdgcn_s_barrier();
            }
        }
    }

    // ---- epilogue ----
    #pragma unroll
    for (int mf = 0; mf < 4; ++mf) {
        int x = mf * 16 + lg * 4;
        #pragma unroll
        for (int nf = 0; nf < NF; ++nf) {
            int ch = wn * HB + nf * 16 + lr;
            float bv = bias[ch];
            if (OUTM == 0) {
                u16* Co = (u16*)Cout;
                int n = (img << 12) + ((y0 + wm) << 6) + x;
                #pragma unroll
                for (int j = 0; j < 4; ++j) {
                    float v = acc[mf][nf][j] + bv;
                    if (do_gelu) v = gelu_f(v);
                    Co[(size_t)(n + j) * ostride + ocol0 + ch] = f2bf(v);
                }
            } else {
                float* Co = (float*)Cout;
                f32x4 vv;
                #pragma unroll
                for (int j = 0; j < 4; ++j)
                    vv[j] = gelu_f(acc[mf][nf][j] + bv);
                *reinterpret_cast<f32x4*>(
                    &Co[((size_t)((img << 6) + ch) << 12) + ((y0 + wm) << 6) + x]) = vv;
            }
        }
    }
}

// ---------------- projection GEMM (rd12 structure, TAPS=1 only) ----------------
template<int TAPS, int CC, int BN, int OUTM>
__global__ __launch_bounds__(256)
void mm_kernel(const u16* __restrict__ A, const u16* __restrict__ Bw,
               const float* __restrict__ bias, void* __restrict__ Cout,
               int ostride, int ocol0, int do_gelu) {
    constexpr int K = CC * TAPS;
    constexpr int NSTEP = TAPS;
    constexpr int NCH = CC / 8;
    constexpr int NKS = CC / 32;
    constexpr int NF = BN / 32;
    constexpr int HN = BN / 2;
    constexpr int RSTEP = 256 / NCH;
    constexpr int ALD = 128 / RSTEP;
    constexpr int BLD = BN / RSTEP;
    __shared__ u16 Als[128 * CC];
    __shared__ u16 Bls[BN * CC];
    const int tid = threadIdx.x;
    const int w = tid >> 6;
    const int lane = tid & 63;
    const int m0 = blockIdx.x * 128;
    const int nt0 = blockIdx.y * BN;
    const int wm = w >> 1, wn = w & 1;

    const int srow = tid / NCH;
    const int sslot = tid % NCH;
    const int csrc = ((sslot ^ (srow & (NCH - 1))) << 3);
    const u16* Bbase = Bw + (size_t)(nt0 + srow) * K + csrc;

    int offA[NKS][4], offB[NKS][NF];
    #pragma unroll
    for (int ks = 0; ks < NKS; ++ks) {
        #pragma unroll
        for (int mf = 0; mf < 4; ++mf) {
            int R = wm * 64 + mf * 16 + (lane & 15);
            int slot = (ks * 4 + (lane >> 4)) ^ (R & (NCH - 1));
            offA[ks][mf] = R * CC + slot * 8;
        }
        #pragma unroll
        for (int nf = 0; nf < NF; ++nf) {
            int Rb = wn * HN + nf * 16 + (lane & 15);
            int slot = (ks * 4 + (lane >> 4)) ^ (Rb & (NCH - 1));
            offB[ks][nf] = Rb * CC + slot * 8;
        }
    }

    f32x4 acc[4][NF];
    #pragma unroll
    for (int i = 0; i < 4; ++i)
        #pragma unroll
        for (int j = 0; j < NF; ++j) {
            f32x4 z = {0.f, 0.f, 0.f, 0.f};
            acc[i][j] = z;
        }

    #pragma unroll
    for (int kt = 0; kt < NSTEP; ++kt) {
        const int kk = kt * CC;
        #pragma unroll
        for (int i = 0; i < ALD; ++i) {
            const int m = m0 + srow + i * RSTEP;
            g2l16(A + (size_t)m * CC + kk + csrc,
                  &Als[(srow + i * RSTEP) * CC + sslot * 8]);
        }
        #pragma unroll
        for (int i = 0; i < BLD; ++i)
            g2l16(Bbase + (size_t)i * RSTEP * K + kk,
                  &Bls[(srow + i * RSTEP) * CC + sslot * 8]);

        __syncthreads();

        #pragma unroll
        for (int ks = 0; ks < NKS; ++ks) {
            bf16x8 af[4];
            #pragma unroll
            for (int mf = 0; mf < 4; ++mf)
                af[mf] = *reinterpret_cast<const bf16x8*>(&Als[offA[ks][mf]]);
            #pragma unroll
            for (int nf = 0; nf < NF; ++nf) {
                bf16x8 bfv = *reinterpret_cast<const bf16x8*>(&Bls[offB[ks][nf]]);
                #pragma unroll
                for (int mf = 0; mf < 4; ++mf)
                    acc[mf][nf] = __builtin_amdgcn_mfma_f32_16x16x32_bf16(
                        af[mf], bfv, acc[mf][nf], 0, 0, 0);
            }
        }
        if (kt + 1 < NSTEP) __syncthreads();
    }

    #pragma unroll
    for (int mf = 0; mf < 4; ++mf) {
        int mrow = m0 + wm * 64 + mf * 16 + (lane >> 4) * 4;
        #pragma unroll
        for (int nf = 0; nf < NF; ++nf) {
            int col = nt0 + wn * HN + nf * 16 + (lane & 15);
            float bv = bias[col];
            u16* Co = (u16*)Cout;
            #pragma unroll
            for (int j = 0; j < 4; ++j) {
                float v = acc[mf][nf][j] + bv;
                if (do_gelu) v = gelu_f(v);
                Co[(size_t)(mrow + j) * ostride + ocol0 + col] = f2bf(v);
            }
        }
    }
}

// ---------------- attention layer 1: heads=8, d=16, 8ch/lane ----------------
__global__ __launch_bounds__(256)
void attn1_kernel(const u16* __restrict__ qkvs, u16* __restrict__ h) {
    const int tid = threadIdx.x;
    const int l16 = tid & 15;
    const int n = blockIdx.x * 16 + (tid >> 4);
    const int y = (n >> 6) & 63, x = n & 63;
    const u32* qk = (const u32*)qkvs;
    const int nbase = (n << 8) + l16 * 4;

    u32x4 qp = *(const u32x4*)(qk + nbase);
    float q[8];
    #pragma unroll
    for (int i = 0; i < 4; ++i) { q[2*i] = blo(qp[i]); q[2*i+1] = bhi(qp[i]); }

    float al[9];
    float mx = -1e30f;
    #pragma unroll
    for (int e = 0; e < 9; ++e) {
        const int dy = e / 3 - 1, dx = e % 3 - 1;
        const bool valid = (unsigned)(y + dy) < 64u && (unsigned)(x + dx) < 64u;
        const int off = valid ? ((dy * 64 + dx) << 8) : 0;
        u32x4 kp = *(const u32x4*)(qk + nbase + off + 64);
        float p = 0.f;
        #pragma unroll
        for (int i = 0; i < 4; ++i) {
            p = fmaf(q[2*i],   blo(kp[i]), p);
            p = fmaf(q[2*i+1], bhi(kp[i]), p);
        }
        p += __shfl_xor(p, 1);
        al[e] = valid ? p * 0.25f : -1e30f;
        mx = fmaxf(mx, al[e]);
    }
    float s = 0.f;
    #pragma unroll
    for (int e = 0; e < 9; ++e) { al[e] = __expf(al[e] - mx); s += al[e]; }

    float o[8] = {0.f, 0.f, 0.f, 0.f, 0.f, 0.f, 0.f, 0.f};
    #pragma unroll
    for (int e = 0; e < 9; ++e) {
        const int dy = e / 3 - 1, dx = e % 3 - 1;
        const bool valid = (unsigned)(y + dy) < 64u && (unsigned)(x + dx) < 64u;
        const int off = valid ? ((dy * 64 + dx) << 8) : 0;
        u32x4 vp = *(const u32x4*)(qk + nbase + off + 128);
        const float a = al[e];
        #pragma unroll
        for (int i = 0; i < 4; ++i) {
            o[2*i]   = fmaf(a, blo(vp[i]), o[2*i]);
            o[2*i+1] = fmaf(a, bhi(vp[i]), o[2*i+1]);
        }
    }
    const float r = __fdividef(1.0f, s + 1e-16f);
    u32x4 sp = *(const u32x4*)(qk + nbase + 192);
    u32x4 res;
    #pragma unroll
    for (int i = 0; i < 4; ++i) {
        float h0 = gelu_f(fmaf(o[2*i],   r, blo(sp[i])));
        float h1 = gelu_f(fmaf(o[2*i+1], r, bhi(sp[i])));
        res[i] = packbf(h0, h1);
    }
    *(u32x4*)((u32*)h + (n << 6) + l16 * 4) = res;
}

// ---------------- attention layer 2: heads=1, d=64, 8ch/lane ----------------
__global__ __launch_bounds__(256)
void attn2_kernel(const u16* __restrict__ qkvs, u16* __restrict__ xc) {
    const int tid = threadIdx.x;
    const int l8 = tid & 7;
    const int n = blockIdx.x * 32 + (tid >> 3);
    const int y = (n >> 6) & 63, x = n & 63;
    const u32* qk = (const u32*)qkvs;
    const int nbase = (n << 7) + l8 * 4;

    u32x4 qp = *(const u32x4*)(qk + nbase);
    float q[8];
    #pragma unroll
    for (int i = 0; i < 4; ++i) { q[2*i] = blo(qp[i]); q[2*i+1] = bhi(qp[i]); }

    float al[9];
    float mx = -1e30f;
    #pragma unroll
    for (int e = 0; e < 9; ++e) {
        const int dy = e / 3 - 1, dx = e % 3 - 1;
        const bool valid = (unsigned)(y + dy) < 64u && (unsigned)(x + dx) < 64u;
        const int off = valid ? ((dy * 64 + dx) << 7) : 0;
        u32x4 kp = *(const u32x4*)(qk + nbase + off + 32);
        float p = 0.f;
        #pragma unroll
        for (int i = 0; i < 4; ++i) {
            p = fmaf(q[2*i],   blo(kp[i]), p);
            p = fmaf(q[2*i+1], bhi(kp[i]), p);
        }
        p += __shfl_xor(p, 1);
        p += __shfl_xor(p, 2);
        p += __shfl_xor(p, 4);
        al[e] = valid ? p * 0.125f : -1e30f;
        mx = fmaxf(mx, al[e]);
    }
    float s = 0.f;
    #pragma unroll
    for (int e = 0; e < 9; ++e) { al[e] = __expf(al[e] - mx); s += al[e]; }

    float o[8] = {0.f, 0.f, 0.f, 0.f, 0.f, 0.f, 0.f, 0.f};
    #pragma unroll
    for (int e = 0; e < 9; ++e) {
        const int dy = e / 3 - 1, dx = e % 3 - 1;
        const bool valid = (unsigned)(y + dy) < 64u && (unsigned)(x + dx) < 64u;
        const int off = valid ? ((dy * 64 + dx) << 7) : 0;
        u32x4 vp = *(const u32x4*)(qk + nbase + off + 64);
        const float a = al[e];
        #pragma unroll
        for (int i = 0; i < 4; ++i) {
            o[2*i]   = fmaf(a, blo(vp[i]), o[2*i]);
            o[2*i+1] = fmaf(a, bhi(vp[i]), o[2*i+1]);
        }
    }
    const float r = __fdividef(1.0f, s + 1e-16f);
    u32x4 sp = *(const u32x4*)(qk + nbase + 96);
    u32x4 res;
    #pragma unroll
    for (int i = 0; i < 4; ++i) {
        float h0 = gelu_f(fmaf(o[2*i],   r, blo(sp[i])));
        float h1 = gelu_f(fmaf(o[2*i+1], r, bhi(sp[i])));
        res[i] = packbf(h0, h1);
    }
    *(u32x4*)((u32*)xc + (n << 6) + 32 + l8 * 4) = res;
}

// ---------------- host launcher ----------------
extern "C" void kernel_launch(void* const* d_in, const int* in_sizes, int n_in,
                              void* d_out, int out_size, void* d_ws, size_t ws_size,
                              hipStream_t stream) {
    const float* x   = (const float*)d_in[0];
    const float* cW1 = (const float*)d_in[1];
    const float* cb1 = (const float*)d_in[2];
    const float* cW2 = (const float*)d_in[3];
    const float* cb2 = (const float*)d_in[4];
    const float* q1W = (const float*)d_in[5];
    const float* q1b = (const float*)d_in[6];
    const float* k1W = (const float*)d_in[7];
    const float* k1b = (const float*)d_in[8];
    const float* v1W = (const float*)d_in[9];
    const float* v1b = (const float*)d_in[10];
    const float* s1W = (const float*)d_in[11];
    const float* s1b = (const float*)d_in[12];
    const float* q2W = (const float*)d_in[13];
    const float* q2b = (const float*)d_in[14];
    const float* k2W = (const float*)d_in[15];
    const float* k2b = (const float*)d_in[16];
    const float* v2W = (const float*)d_in[17];
    const float* v2b = (const float*)d_in[18];
    const float* s2W = (const float*)d_in[19];
    const float* s2b = (const float*)d_in[20];
    const float* fW1 = (const float*)d_in[21];
    const float* fb1 = (const float*)d_in[22];
    const float* fW2 = (const float*)d_in[23];
    const float* fb2 = (const float*)d_in[24];

    char* ws = (char*)d_ws;
    float* sig  = (float*)(ws + SIG);
    float* b1   = (float*)(ws + B1OFF);
    float* b2   = (float*)(ws + B2OFF);
    u16* wc1    = (u16*)(ws + WC1);
    u16* wc2    = (u16*)(ws + WC2);
    u16* wf1    = (u16*)(ws + WF1);
    u16* wf2    = (u16*)(ws + WF2);
    u16* wp1    = (u16*)(ws + WP1);
    u16* wp2    = (u16*)(ws + WP2);
    u16* xb     = (u16*)(ws + XB);
    u16* hbuf   = (u16*)(ws + HBUF);
    u16* qkvs2  = (u16*)(ws + QKVS2);
    u16* xc     = (u16*)(ws + XC);
    u16* qkvs1  = (u16*)(ws + QKVS1);
    u16* y1     = (u16*)(ws + Y1);
    u16* tbuf   = (u16*)(ws + TBUF);
    float* gram = (float*)(ws + GRAM);
    float* out  = (float*)d_out;

    gram_kernel<<<160, 256, 0, stream>>>(cW1, cW2, fW1, fW2, gram);
    power_kernel<<<4, 256, 0, stream>>>(gram, sig);
    prep_conv_w<<<dim3(576, 4), 256, 0, stream>>>(cW1, cW2, fW1, fW2, sig,
                                                  wc1, wc2, wf1, wf2);
    prep_proj<<<260, 256, 0, stream>>>(q1W, k1W, v1W, s1W, q2W, k2W, v2W, s2W,
                                       q1b, k1b, v1b, s1b, q2b, k2b, v2b, s2b,
                                       wp1, wp2, b1, b2);
    convert_x<<<1024, 256, 0, stream>>>(x, xb);

    // proj1: [N][64] x [512][64]^T -> qkvs1 [N][512]   (1 step)
    mm_kernel<1, 64, 128, 0><<<dim3(512, 4), 256, 0, stream>>>(
        xb, wp1, b1, qkvs1, 512, 0, 0);
    attn1_kernel<<<NPIX / 16, 256, 0, stream>>>(qkvs1, hbuf);
    // proj2: [N][128] x [256][128]^T -> qkvs2 [N][256]  (1 step)
    mm_kernel<1, 128, 128, 0><<<dim3(512, 2), 256, 0, stream>>>(
        hbuf, wp2, b2, qkvs2, 256, 0, 0);
    attn2_kernel<<<NPIX / 32, 256, 0, stream>>>(qkvs2, xc);

    // conv1: xb (C=64) -> y1 [N][128], gelu
    conv_kernel<64, 1, 128, 0><<<256, 512, 0, stream>>>(xb, wc1, cb1, y1, 128, 0, 1);
    // conv2: y1 (C=128) -> xc cols 0..63, gelu
    conv_kernel<128, 2, 64, 0><<<256, 512, 0, stream>>>(y1, wc2, cb2, xc, 128, 0, 1);
    // conv3: xc (C=128) -> tbuf [N][128], gelu
    conv_kernel<128, 2, 128, 0><<<256, 512, 0, stream>>>(xc, wf1, fb1, tbuf, 128, 0, 1);
    // conv4: tbuf (C=128) -> out f32 NCHW, gelu
    conv_kernel<128, 2, 64, 1><<<256, 512, 0, stream>>>(tbuf, wf2, fb2, out, 0, 0, 1);
}

// Round 15
// 193.235 us; speedup vs baseline: 1.0936x; 1.0936x over previous
//
#include <hip/hip_runtime.h>
#include <hip/hip_bf16.h>

typedef unsigned int  u32;
typedef unsigned short u16;
typedef __attribute__((ext_vector_type(8))) short bf16x8;
typedef __attribute__((ext_vector_type(4))) float f32x4;
typedef __attribute__((ext_vector_type(4))) u32 u32x4;

#define NPIX 65536

// ---------------- ws byte offsets ----------------
constexpr size_t SIG   = 0;
constexpr size_t B1OFF = 256;
constexpr size_t B2OFF = B1OFF + 2048;
constexpr size_t WC1   = B2OFF + 1024;        // 128x576 bf16
constexpr size_t WC2   = WC1 + 147456;        // 64x1152
constexpr size_t WF1   = WC2 + 147456;        // 128x1152
constexpr size_t WF2   = WF1 + 294912;        // 64x1152
constexpr size_t WP1   = WF2 + 147456;        // 512x64
constexpr size_t WP2   = WP1 + 65536;         // 256x128
constexpr size_t XB    = WP2 + 65536;         // 65536x64 bf16
constexpr size_t HBUF  = XB + 8388608;        // 65536x128 bf16
constexpr size_t QKVS2 = HBUF + 16777216;     // 65536x256 bf16
constexpr size_t XC    = QKVS2 + 33554432;    // 65536x128 bf16 concat
constexpr size_t QKVS1 = XC + 16777216;       // 65536x512 bf16
constexpr size_t TBUF  = QKVS1 + 16777216;    // alias into dead qkvs1 (D6 only)
constexpr size_t GRAM  = QKVS1 + 67108864;
// NOTE: y1 (conv1 out, 16.78MB) lives in d_out, which is dead until conv4
// rewrites every element (alias-free fusion; rd14's y1=QKVS1 raced attn1).

// ---------------- helpers ----------------
__device__ __forceinline__ float gelu_f(float v) {
    float xa = fabsf(v) * 0.70710678118654752f;
    float t  = __fdividef(1.0f, fmaf(0.3275911f, xa, 1.0f));
    float poly = t * fmaf(t, fmaf(t, fmaf(t, fmaf(t, 1.061405429f, -1.453152027f),
                   1.421413741f), -0.284496736f), 0.254829592f);
    float erfv = 1.0f - poly * __expf(-xa * xa);
    erfv = copysignf(erfv, v);
    return 0.5f * v * (1.0f + erfv);
}
__device__ __forceinline__ u16 f2bf(float f) {
    __hip_bfloat16 b = __float2bfloat16(f);
    return *reinterpret_cast<u16*>(&b);
}
__device__ __forceinline__ float blo(u32 u) {
    union { u32 i; float f; } x; x.i = u << 16; return x.f;
}
__device__ __forceinline__ float bhi(u32 u) {
    union { u32 i; float f; } x; x.i = u & 0xffff0000u; return x.f;
}
__device__ __forceinline__ u32 packbf(float a, float b) {
    return (u32)f2bf(a) | ((u32)f2bf(b) << 16);
}
__device__ __forceinline__ void g2l16(const void* g, void* l) {
    __builtin_amdgcn_global_load_lds(
        (const __attribute__((address_space(1))) u32*)g,
        (__attribute__((address_space(3))) u32*)l, 16, 0, 0);
}

// ---------------- block reduction ----------------
__device__ float block_sum(float vv, float* red) {
    #pragma unroll
    for (int m = 1; m < 64; m <<= 1) vv += __shfl_xor(vv, m);
    int tid = threadIdx.x;
    __syncthreads();
    if ((tid & 63) == 0) red[tid >> 6] = vv;
    __syncthreads();
    return red[0] + red[1] + red[2] + red[3];
}

// ================= device bodies (shared memory passed in) =================

// ---- Gram: G_w = W_w W_w^T tile (needs 4224B smem) ----
__device__ void gram_body(int bid, char* smem,
                          const float* cW1, const float* cW2,
                          const float* fW1, const float* fW2, float* Gall) {
    const float* W; int O, K, wsel, tile;
    if (bid < 64)       { W = cW1; O = 128; K = 576;  wsel = 0; tile = bid; }
    else if (bid < 80)  { W = cW2; O = 64;  K = 1152; wsel = 1; tile = bid - 64; }
    else if (bid < 144) { W = fW1; O = 128; K = 1152; wsel = 2; tile = bid - 80; }
    else                { W = fW2; O = 64;  K = 1152; wsel = 3; tile = bid - 144; }
    int ntiles = O >> 4;
    int ti0 = (tile / ntiles) << 4, tj0 = (tile % ntiles) << 4;
    float (*Wi)[33] = (float(*)[33])smem;
    float (*Wj)[33] = (float(*)[33])(smem + 16 * 33 * 4);
    int tid = threadIdx.x;
    int ti = tid >> 4, tj = tid & 15;
    int r = tid >> 5, c = tid & 31;
    float acc = 0.f;
    for (int k0 = 0; k0 < K; k0 += 32) {
        Wi[r][c]     = W[(size_t)(ti0 + r) * K + k0 + c];
        Wi[r + 8][c] = W[(size_t)(ti0 + r + 8) * K + k0 + c];
        Wj[r][c]     = W[(size_t)(tj0 + r) * K + k0 + c];
        Wj[r + 8][c] = W[(size_t)(tj0 + r + 8) * K + k0 + c];
        __syncthreads();
        #pragma unroll
        for (int k = 0; k < 32; ++k)
            acc += Wi[ti][k] * Wj[tj][k];
        __syncthreads();
    }
    Gall[wsel * 16384 + (ti0 + ti) * 128 + (tj0 + tj)] = acc;
}

// ---- x NCHW f32 -> [pix][64] bf16 (needs 16640B smem) ----
__device__ void convert_body(int bid, char* smem,
                             const float* __restrict__ x, u16* __restrict__ xb) {
    float (*tile)[65] = (float(*)[65])smem;
    int b = bid >> 6, y = bid & 63;
    int tid = threadIdx.x;
    #pragma unroll
    for (int i = 0; i < 16; ++i) {
        int c = (tid >> 6) + i * 4;
        tile[c][tid & 63] = x[(((size_t)b * 64 + c) << 12) + (y << 6) + (tid & 63)];
    }
    __syncthreads();
    #pragma unroll
    for (int i = 0; i < 16; ++i) {
        int idx = tid + i * 256;
        int p = idx >> 6, c = idx & 63;
        xb[(((size_t)b << 12) + (y << 6) + p) * 64 + c] = f2bf(tile[c][p]);
    }
}

// ---- projection weight/bias prep (no smem) ----
__device__ void prep_proj_body(int bid,
               const float* q1W, const float* k1W, const float* v1W, const float* s1W,
               const float* q2W, const float* k2W, const float* v2W, const float* s2W,
               const float* q1b, const float* k1b, const float* v1b, const float* s1b,
               const float* q2b, const float* k2b, const float* v2b, const float* s2b,
               u16* wp1, u16* wp2, float* b1, float* b2) {
    const float* W1[4] = {q1W, k1W, v1W, s1W};
    const float* W2[4] = {q2W, k2W, v2W, s2W};
    const float* Bb1[4] = {q1b, k1b, v1b, s1b};
    const float* Bb2[4] = {q2b, k2b, v2b, s2b};
    int idx = bid * 256 + threadIdx.x;
    if (idx < 32768) {
        int w = idx >> 13, r = idx & 8191;
        wp1[(size_t)w * 8192 + r] = f2bf(W1[w][r]);
    } else if (idx < 65536) {
        int j = idx - 32768; int w = j >> 13, r = j & 8191;
        wp2[(size_t)w * 8192 + r] = f2bf(W2[w][r]);
    } else if (idx < 66048) {
        int j = idx - 65536; int w = j >> 7; b1[j] = Bb1[w][j & 127];
    } else if (idx < 66304) {
        int j = idx - 66048; int w = j >> 6; b2[j] = Bb2[w][j & 63];
    }
}

// ---- conv weight prep (no smem) ----
__device__ void prep_conv_w_body(int bx, int wsel,
                 const float* __restrict__ cW1, const float* __restrict__ cW2,
                 const float* __restrict__ fW1, const float* __restrict__ fW2,
                 const float* __restrict__ sig,
                 u16* wc1, u16* wc2, u16* wf1, u16* wf2) {
    const float* src; u16* dst; int O, C;
    switch (wsel) {
        case 0:  src = cW1; dst = wc1; O = 128; C = 64;  break;
        case 1:  src = cW2; dst = wc2; O = 64;  C = 128; break;
        case 2:  src = fW1; dst = wf1; O = 128; C = 128; break;
        default: src = fW2; dst = wf2; O = 64;  C = 128; break;
    }
    int idx = bx * 256 + threadIdx.x;
    if (idx >= O * C * 9) return;
    int o = idx / (C * 9);
    int rem = idx - o * (C * 9);
    int ci = rem / 9, tap = rem - ci * 9;
    float v = src[idx] / sig[wsel];
    dst[(size_t)o * (C * 9) + tap * C + ci] = f2bf(v);
}

// ---- bf16 MFMA GEMM, implicit im2col, BK=CC (rd12 structure) ----
template<int TAPS, int CC, int BN, int OUTM>
__device__ void mm_body(int bx, int by, char* smem,
               const u16* __restrict__ A, const u16* __restrict__ Bw,
               const float* __restrict__ bias, void* __restrict__ Cout,
               int ostride, int ocol0, int do_gelu) {
    constexpr int K = CC * TAPS;
    constexpr int NSTEP = TAPS;
    constexpr int NCH = CC / 8;
    constexpr int NKS = CC / 32;
    constexpr int NF = BN / 32;
    constexpr int HN = BN / 2;
    constexpr int RSTEP = 256 / NCH;
    constexpr int ALD = 128 / RSTEP;
    constexpr int BLD = BN / RSTEP;
    u16* Als = (u16*)smem;
    u16* Bls = (u16*)smem + 128 * CC;
    const int tid = threadIdx.x;
    const int w = tid >> 6;
    const int lane = tid & 63;
    const int m0 = bx * 128;
    const int nt0 = by * BN;
    const int wm = w >> 1, wn = w & 1;

    const int srow = tid / NCH;
    const int sslot = tid % NCH;
    const int csrc = ((sslot ^ (srow & (NCH - 1))) << 3);
    const u16* Bbase = Bw + (size_t)(nt0 + srow) * K + csrc;

    int offA[NKS][4], offB[NKS][NF];
    #pragma unroll
    for (int ks = 0; ks < NKS; ++ks) {
        #pragma unroll
        for (int mf = 0; mf < 4; ++mf) {
            int R = wm * 64 + mf * 16 + (lane & 15);
            int slot = (ks * 4 + (lane >> 4)) ^ (R & (NCH - 1));
            offA[ks][mf] = R * CC + slot * 8;
        }
        #pragma unroll
        for (int nf = 0; nf < NF; ++nf) {
            int Rb = wn * HN + nf * 16 + (lane & 15);
            int slot = (ks * 4 + (lane >> 4)) ^ (Rb & (NCH - 1));
            offB[ks][nf] = Rb * CC + slot * 8;
        }
    }

    f32x4 acc[4][NF];
    #pragma unroll
    for (int i = 0; i < 4; ++i)
        #pragma unroll
        for (int j = 0; j < NF; ++j) {
            f32x4 z = {0.f, 0.f, 0.f, 0.f};
            acc[i][j] = z;
        }

    #pragma unroll
    for (int kt = 0; kt < NSTEP; ++kt) {
        const int kk = kt * CC;
        const int dy = (TAPS == 9) ? (kt / 3 - 1) : 0;
        const int dx = (TAPS == 9) ? (kt % 3 - 1) : 0;
        #pragma unroll
        for (int i = 0; i < ALD; ++i) {
            const int m = m0 + srow + i * RSTEP;
            const u16* ga;
            if constexpr (TAPS == 9) {
                int yy = ((m >> 6) & 63) + dy; yy = min(max(yy, 0), 63);
                int xx = (m & 63) + dx;        xx = min(max(xx, 0), 63);
                ga = A + (size_t)((m & ~4095) | (yy << 6) | xx) * CC + csrc;
            } else {
                ga = A + (size_t)m * CC + csrc;
            }
            g2l16(ga, &Als[(srow + i * RSTEP) * CC + sslot * 8]);
        }
        #pragma unroll
        for (int i = 0; i < BLD; ++i)
            g2l16(Bbase + (size_t)i * RSTEP * K + kk,
                  &Bls[(srow + i * RSTEP) * CC + sslot * 8]);

        __syncthreads();

        #pragma unroll
        for (int ks = 0; ks < NKS; ++ks) {
            bf16x8 af[4];
            #pragma unroll
            for (int mf = 0; mf < 4; ++mf)
                af[mf] = *reinterpret_cast<const bf16x8*>(&Als[offA[ks][mf]]);
            #pragma unroll
            for (int nf = 0; nf < NF; ++nf) {
                bf16x8 bfv = *reinterpret_cast<const bf16x8*>(&Bls[offB[ks][nf]]);
                #pragma unroll
                for (int mf = 0; mf < 4; ++mf)
                    acc[mf][nf] = __builtin_amdgcn_mfma_f32_16x16x32_bf16(
                        af[mf], bfv, acc[mf][nf], 0, 0, 0);
            }
        }
        if (kt + 1 < NSTEP) __syncthreads();
    }

    #pragma unroll
    for (int mf = 0; mf < 4; ++mf) {
        int mrow = m0 + wm * 64 + mf * 16 + (lane >> 4) * 4;
        #pragma unroll
        for (int nf = 0; nf < NF; ++nf) {
            int col = nt0 + wn * HN + nf * 16 + (lane & 15);
            float bv = bias[col];
            if (OUTM == 0) {
                u16* Co = (u16*)Cout;
                #pragma unroll
                for (int j = 0; j < 4; ++j) {
                    float v = acc[mf][nf][j] + bv;
                    if (do_gelu) v = gelu_f(v);
                    Co[(size_t)(mrow + j) * ostride + ocol0 + col] = f2bf(v);
                }
            } else {
                float* Co = (float*)Cout;
                int b = m0 >> 12;
                int pixb = (mrow & 4095);
                f32x4 vv;
                #pragma unroll
                for (int j = 0; j < 4; ++j)
                    vv[j] = gelu_f(acc[mf][nf][j] + bv);
                *reinterpret_cast<f32x4*>(&Co[((size_t)(b * 64 + col)) * 4096 + pixb]) = vv;
            }
        }
    }
}

// ---- attention layer 1 body (no smem) ----
__device__ void attn1_body(int bid, const u16* __restrict__ qkvs,
                           u16* __restrict__ h) {
    const int tid = threadIdx.x;
    const int l16 = tid & 15;
    const int n = bid * 16 + (tid >> 4);
    const int y = (n >> 6) & 63, x = n & 63;
    const u32* qk = (const u32*)qkvs;
    const int nbase = (n << 8) + l16 * 4;

    u32x4 qp = *(const u32x4*)(qk + nbase);
    float q[8];
    #pragma unroll
    for (int i = 0; i < 4; ++i) { q[2*i] = blo(qp[i]); q[2*i+1] = bhi(qp[i]); }

    float al[9];
    float mx = -1e30f;
    #pragma unroll
    for (int e = 0; e < 9; ++e) {
        const int dy = e / 3 - 1, dx = e % 3 - 1;
        const bool valid = (unsigned)(y + dy) < 64u && (unsigned)(x + dx) < 64u;
        const int off = valid ? ((dy * 64 + dx) << 8) : 0;
        u32x4 kp = *(const u32x4*)(qk + nbase + off + 64);
        float p = 0.f;
        #pragma unroll
        for (int i = 0; i < 4; ++i) {
            p = fmaf(q[2*i],   blo(kp[i]), p);
            p = fmaf(q[2*i+1], bhi(kp[i]), p);
        }
        p += __shfl_xor(p, 1);
        al[e] = valid ? p * 0.25f : -1e30f;
        mx = fmaxf(mx, al[e]);
    }
    float s = 0.f;
    #pragma unroll
    for (int e = 0; e < 9; ++e) { al[e] = __expf(al[e] - mx); s += al[e]; }

    float o[8] = {0.f, 0.f, 0.f, 0.f, 0.f, 0.f, 0.f, 0.f};
    #pragma unroll
    for (int e = 0; e < 9; ++e) {
        const int dy = e / 3 - 1, dx = e % 3 - 1;
        const bool valid = (unsigned)(y + dy) < 64u && (unsigned)(x + dx) < 64u;
        const int off = valid ? ((dy * 64 + dx) << 8) : 0;
        u32x4 vp = *(const u32x4*)(qk + nbase + off + 128);
        const float a = al[e];
        #pragma unroll
        for (int i = 0; i < 4; ++i) {
            o[2*i]   = fmaf(a, blo(vp[i]), o[2*i]);
            o[2*i+1] = fmaf(a, bhi(vp[i]), o[2*i+1]);
        }
    }
    const float r = __fdividef(1.0f, s + 1e-16f);
    u32x4 sp = *(const u32x4*)(qk + nbase + 192);
    u32x4 res;
    #pragma unroll
    for (int i = 0; i < 4; ++i) {
        float h0 = gelu_f(fmaf(o[2*i],   r, blo(sp[i])));
        float h1 = gelu_f(fmaf(o[2*i+1], r, bhi(sp[i])));
        res[i] = packbf(h0, h1);
    }
    *(u32x4*)((u32*)h + (n << 6) + l16 * 4) = res;
}

// ================= global wrappers =================

// power iteration (standalone)
__global__ __launch_bounds__(256)
void power_kernel(const float* __restrict__ Gall, float* __restrict__ sig) {
    int wsel = blockIdx.x;
    const float* G = Gall + wsel * 16384;
    const int O = (wsel == 0 || wsel == 2) ? 128 : 64;
    __shared__ float u[128], t[128], red[4];
    int tid = threadIdx.x;
    if (tid < O) u[tid] = 1.0f / sqrtf((float)O);
    __syncthreads();
    for (int it = 0; it < 3; ++it) {
        if (tid < O) {
            float s = 0.f;
            const float4* gr = reinterpret_cast<const float4*>(G + (size_t)tid * 128);
            for (int j = 0; j < O / 4; ++j) {
                float4 g = gr[j];
                s += g.x * u[4*j] + g.y * u[4*j+1] + g.z * u[4*j+2] + g.w * u[4*j+3];
            }
            t[tid] = s;
        }
        __syncthreads();
        float loc = (tid < O) ? t[tid] * t[tid] : 0.f;
        float nt = sqrtf(block_sum(loc, red));
        if (it == 2) {
            float locd = (tid < O) ? u[tid] * t[tid] : 0.f;
            float dot = block_sum(locd, red);
            if (tid == 0) sig[wsel] = nt / sqrtf(dot + 1e-24f);
        } else {
            if (tid < O) u[tid] = t[tid] / (nt + 1e-12f);
            __syncthreads();
        }
    }
}

// attention layer 2 (standalone)
__global__ __launch_bounds__(256)
void attn2_kernel(const u16* __restrict__ qkvs, u16* __restrict__ xc) {
    const int tid = threadIdx.x;
    const int l8 = tid & 7;
    const int n = blockIdx.x * 32 + (tid >> 3);
    const int y = (n >> 6) & 63, x = n & 63;
    const u32* qk = (const u32*)qkvs;
    const int nbase = (n << 7) + l8 * 4;

    u32x4 qp = *(const u32x4*)(qk + nbase);
    float q[8];
    #pragma unroll
    for (int i = 0; i < 4; ++i) { q[2*i] = blo(qp[i]); q[2*i+1] = bhi(qp[i]); }

    float al[9];
    float mx = -1e30f;
    #pragma unroll
    for (int e = 0; e < 9; ++e) {
        const int dy = e / 3 - 1, dx = e % 3 - 1;
        const bool valid = (unsigned)(y + dy) < 64u && (unsigned)(x + dx) < 64u;
        const int off = valid ? ((dy * 64 + dx) << 7) : 0;
        u32x4 kp = *(const u32x4*)(qk + nbase + off + 32);
        float p = 0.f;
        #pragma unroll
        for (int i = 0; i < 4; ++i) {
            p = fmaf(q[2*i],   blo(kp[i]), p);
            p = fmaf(q[2*i+1], bhi(kp[i]), p);
        }
        p += __shfl_xor(p, 1);
        p += __shfl_xor(p, 2);
        p += __shfl_xor(p, 4);
        al[e] = valid ? p * 0.125f : -1e30f;
        mx = fmaxf(mx, al[e]);
    }
    float s = 0.f;
    #pragma unroll
    for (int e = 0; e < 9; ++e) { al[e] = __expf(al[e] - mx); s += al[e]; }

    float o[8] = {0.f, 0.f, 0.f, 0.f, 0.f, 0.f, 0.f, 0.f};
    #pragma unroll
    for (int e = 0; e < 9; ++e) {
        const int dy = e / 3 - 1, dx = e % 3 - 1;
        const bool valid = (unsigned)(y + dy) < 64u && (unsigned)(x + dx) < 64u;
        const int off = valid ? ((dy * 64 + dx) << 7) : 0;
        u32x4 vp = *(const u32x4*)(qk + nbase + off + 64);
        const float a = al[e];
        #pragma unroll
        for (int i = 0; i < 4; ++i) {
            o[2*i]   = fmaf(a, blo(vp[i]), o[2*i]);
            o[2*i+1] = fmaf(a, bhi(vp[i]), o[2*i+1]);
        }
    }
    const float r = __fdividef(1.0f, s + 1e-16f);
    u32x4 sp = *(const u32x4*)(qk + nbase + 96);
    u32x4 res;
    #pragma unroll
    for (int i = 0; i < 4; ++i) {
        float h0 = gelu_f(fmaf(o[2*i],   r, blo(sp[i])));
        float h1 = gelu_f(fmaf(o[2*i+1], r, bhi(sp[i])));
        res[i] = packbf(h0, h1);
    }
    *(u32x4*)((u32*)xc + (n << 6) + 32 + l8 * 4) = res;
}

// standalone GEMM wrapper (conv3, conv4)
template<int TAPS, int CC, int BN, int OUTM>
__global__ __launch_bounds__(256)
void mm_kernel(const u16* __restrict__ A, const u16* __restrict__ Bw,
               const float* __restrict__ bias, void* __restrict__ Cout,
               int ostride, int ocol0, int do_gelu) {
    __shared__ __align__(16) char smem[(128 * CC + BN * CC) * 2];
    mm_body<TAPS, CC, BN, OUTM>(blockIdx.x, blockIdx.y, smem, A, Bw, bias, Cout,
                                ostride, ocol0, do_gelu);
}

// D0: convert_x (1024) || gram (160) || prep_proj (260)
__global__ __launch_bounds__(256)
void fuse_misc(const float* cW1, const float* cW2, const float* fW1,
               const float* fW2, float* Gall,
               const float* x, u16* xb,
               const float* q1W, const float* k1W, const float* v1W, const float* s1W,
               const float* q2W, const float* k2W, const float* v2W, const float* s2W,
               const float* q1b, const float* k1b, const float* v1b, const float* s1b,
               const float* q2b, const float* k2b, const float* v2b, const float* s2b,
               u16* wp1, u16* wp2, float* b1, float* b2) {
    __shared__ __align__(16) char smem[16640];
    int bid = blockIdx.x;
    if (bid < 1024)       convert_body(bid, smem, x, xb);
    else if (bid < 1184)  gram_body(bid - 1024, smem, cW1, cW2, fW1, fW2, Gall);
    else                  prep_proj_body(bid - 1184, q1W, k1W, v1W, s1W,
                                         q2W, k2W, v2W, s2W, q1b, k1b, v1b, s1b,
                                         q2b, k2b, v2b, s2b, wp1, wp2, b1, b2);
}

// D2: proj1 (2048) || prep_conv_w (2304)
__global__ __launch_bounds__(256)
void fuse_p1_w(const u16* xb, const u16* wp1, const float* b1, u16* qkvs1,
               const float* cW1, const float* cW2, const float* fW1,
               const float* fW2, const float* sig,
               u16* wc1, u16* wc2, u16* wf1, u16* wf2) {
    __shared__ __align__(16) char smem[(128 * 64 + 128 * 64) * 2];
    int bid = blockIdx.x;
    if (bid < 2048)
        mm_body<1, 64, 128, 0>(bid & 511, bid >> 9, smem, xb, wp1, b1,
                               (void*)qkvs1, 512, 0, 0);
    else {
        int wk = bid - 2048;
        prep_conv_w_body(wk % 576, wk / 576, cW1, cW2, fW1, fW2, sig,
                         wc1, wc2, wf1, wf2);
    }
}

// D3: conv1 (512, writes y1 in d_out) || attn1 (4096)
__global__ __launch_bounds__(256)
void fuse_c1_a1(const u16* xb, const u16* wc1, const float* cb1, u16* y1,
                const u16* qkvs1, u16* hbuf) {
    __shared__ __align__(16) char smem[(128 * 64 + 128 * 64) * 2];
    int bid = blockIdx.x;
    if (bid < 512)
        mm_body<9, 64, 128, 0>(bid, 0, smem, xb, wc1, cb1, (void*)y1, 128, 0, 1);
    else
        attn1_body(bid - 512, qkvs1, hbuf);
}

// D4: conv2 (512, reads y1 in d_out) || proj2 (1024)
__global__ __launch_bounds__(256)
void fuse_c2_p2(const u16* y1, const u16* wc2, const float* cb2, u16* xc,
                const u16* hbuf, const u16* wp2, const float* b2, u16* qkvs2) {
    __shared__ __align__(16) char smem[(128 * 128 + 128 * 128) * 2];
    int bid = blockIdx.x;
    if (bid < 512)
        mm_body<9, 128, 64, 0>(bid, 0, smem, y1, wc2, cb2, (void*)xc, 128, 0, 1);
    else {
        int wk = bid - 512;
        mm_body<1, 128, 128, 0>(wk & 511, wk >> 9, smem, hbuf, wp2, b2,
                                (void*)qkvs2, 256, 0, 0);
    }
}

// ---------------- host launcher ----------------
extern "C" void kernel_launch(void* const* d_in, const int* in_sizes, int n_in,
                              void* d_out, int out_size, void* d_ws, size_t ws_size,
                              hipStream_t stream) {
    const float* x   = (const float*)d_in[0];
    const float* cW1 = (const float*)d_in[1];
    const float* cb1 = (const float*)d_in[2];
    const float* cW2 = (const float*)d_in[3];
    const float* cb2 = (const float*)d_in[4];
    const float* q1W = (const float*)d_in[5];
    const float* q1b = (const float*)d_in[6];
    const float* k1W = (const float*)d_in[7];
    const float* k1b = (const float*)d_in[8];
    const float* v1W = (const float*)d_in[9];
    const float* v1b = (const float*)d_in[10];
    const float* s1W = (const float*)d_in[11];
    const float* s1b = (const float*)d_in[12];
    const float* q2W = (const float*)d_in[13];
    const float* q2b = (const float*)d_in[14];
    const float* k2W = (const float*)d_in[15];
    const float* k2b = (const float*)d_in[16];
    const float* v2W = (const float*)d_in[17];
    const float* v2b = (const float*)d_in[18];
    const float* s2W = (const float*)d_in[19];
    const float* s2b = (const float*)d_in[20];
    const float* fW1 = (const float*)d_in[21];
    const float* fb1 = (const float*)d_in[22];
    const float* fW2 = (const float*)d_in[23];
    const float* fb2 = (const float*)d_in[24];

    char* ws = (char*)d_ws;
    float* sig  = (float*)(ws + SIG);
    float* b1   = (float*)(ws + B1OFF);
    float* b2   = (float*)(ws + B2OFF);
    u16* wc1    = (u16*)(ws + WC1);
    u16* wc2    = (u16*)(ws + WC2);
    u16* wf1    = (u16*)(ws + WF1);
    u16* wf2    = (u16*)(ws + WF2);
    u16* wp1    = (u16*)(ws + WP1);
    u16* wp2    = (u16*)(ws + WP2);
    u16* xb     = (u16*)(ws + XB);
    u16* hbuf   = (u16*)(ws + HBUF);
    u16* qkvs2  = (u16*)(ws + QKVS2);
    u16* xc     = (u16*)(ws + XC);
    u16* qkvs1  = (u16*)(ws + QKVS1);
    u16* tbuf   = (u16*)(ws + TBUF);
    float* gram = (float*)(ws + GRAM);
    float* out  = (float*)d_out;
    u16* y1     = (u16*)d_out;   // y1 scratch: dead until conv4 rewrites out fully

    // D0: convert_x || gram || prep_proj
    fuse_misc<<<1444, 256, 0, stream>>>(cW1, cW2, fW1, fW2, gram, x, xb,
        q1W, k1W, v1W, s1W, q2W, k2W, v2W, s2W,
        q1b, k1b, v1b, s1b, q2b, k2b, v2b, s2b, wp1, wp2, b1, b2);
    // D1: power iteration
    power_kernel<<<4, 256, 0, stream>>>(gram, sig);
    // D2: proj1 || prep_conv_w
    fuse_p1_w<<<4352, 256, 0, stream>>>(xb, wp1, b1, qkvs1,
        cW1, cW2, fW1, fW2, sig, wc1, wc2, wf1, wf2);
    // D3: conv1 (-> y1 in d_out) || attn1
    fuse_c1_a1<<<4608, 256, 0, stream>>>(xb, wc1, cb1, y1, qkvs1, hbuf);
    // D4: conv2 || proj2
    fuse_c2_p2<<<1536, 256, 0, stream>>>(y1, wc2, cb2, xc, hbuf, wp2, b2, qkvs2);
    // D5: attn2 -> xc cols 64..127
    attn2_kernel<<<NPIX / 32, 256, 0, stream>>>(qkvs2, xc);
    // D6: conv3 (tbuf aliases dead qkvs1)
    mm_kernel<9, 128, 128, 0><<<dim3(512, 1), 256, 0, stream>>>(
        xc, wf1, fb1, tbuf, 128, 0, 1);
    // D7: conv4 (rewrites every element of d_out)
    mm_kernel<9, 128, 64, 1><<<dim3(512, 1), 256, 0, stream>>>(
        tbuf, wf2, fb2, out, 0, 0, 1);
}

// Round 16
// 188.993 us; speedup vs baseline: 1.1182x; 1.0224x over previous
//
#include <hip/hip_runtime.h>
#include <hip/hip_bf16.h>

typedef unsigned int  u32;
typedef unsigned short u16;
typedef __attribute__((ext_vector_type(8))) short bf16x8;
typedef __attribute__((ext_vector_type(4))) float f32x4;
typedef __attribute__((ext_vector_type(4))) u32 u32x4;

#define NPIX 65536

// ---------------- ws byte offsets ----------------
constexpr size_t SIG   = 0;
constexpr size_t B1OFF = 256;
constexpr size_t B2OFF = B1OFF + 2048;
constexpr size_t WC1   = B2OFF + 1024;        // 128x576 bf16
constexpr size_t WC2   = WC1 + 147456;        // 64x1152
constexpr size_t WF1   = WC2 + 147456;        // 128x1152
constexpr size_t WF2   = WF1 + 294912;        // 64x1152
constexpr size_t WP1   = WF2 + 147456;        // 512x64
constexpr size_t WP2   = WP1 + 65536;         // 256x128
constexpr size_t XB    = WP2 + 65536;         // 65536x64 bf16
constexpr size_t HBUF  = XB + 8388608;        // 65536x128 bf16
constexpr size_t QKVS2 = HBUF + 16777216;     // 65536x256 bf16
constexpr size_t XC    = QKVS2 + 33554432;    // 65536x128 bf16 concat
constexpr size_t QKVS1 = XC + 16777216;       // 65536x512 bf16
constexpr size_t TBUF  = QKVS1 + 16777216;    // alias into dead qkvs1 (D6 only)
constexpr size_t GRAM  = QKVS1 + 67108864;
// y1 (conv1 out) lives in d_out (dead until conv4 rewrites every element).

// ---------------- helpers ----------------
__device__ __forceinline__ float gelu_f(float v) {
    float xa = fabsf(v) * 0.70710678118654752f;
    float t  = __fdividef(1.0f, fmaf(0.3275911f, xa, 1.0f));
    float poly = t * fmaf(t, fmaf(t, fmaf(t, fmaf(t, 1.061405429f, -1.453152027f),
                   1.421413741f), -0.284496736f), 0.254829592f);
    float erfv = 1.0f - poly * __expf(-xa * xa);
    erfv = copysignf(erfv, v);
    return 0.5f * v * (1.0f + erfv);
}
__device__ __forceinline__ u16 f2bf(float f) {
    __hip_bfloat16 b = __float2bfloat16(f);
    return *reinterpret_cast<u16*>(&b);
}
__device__ __forceinline__ float blo(u32 u) {
    union { u32 i; float f; } x; x.i = u << 16; return x.f;
}
__device__ __forceinline__ float bhi(u32 u) {
    union { u32 i; float f; } x; x.i = u & 0xffff0000u; return x.f;
}
__device__ __forceinline__ u32 packbf(float a, float b) {
    return (u32)f2bf(a) | ((u32)f2bf(b) << 16);
}
__device__ __forceinline__ void g2l16(const void* g, void* l) {
    __builtin_amdgcn_global_load_lds(
        (const __attribute__((address_space(1))) u32*)g,
        (__attribute__((address_space(3))) u32*)l, 16, 0, 0);
}

// ---------------- block reduction ----------------
__device__ float block_sum(float vv, float* red) {
    #pragma unroll
    for (int m = 1; m < 64; m <<= 1) vv += __shfl_xor(vv, m);
    int tid = threadIdx.x;
    __syncthreads();
    if ((tid & 63) == 0) red[tid >> 6] = vv;
    __syncthreads();
    return red[0] + red[1] + red[2] + red[3];
}

// ================= device bodies =================

// ---- Gram tile (4224B smem) ----
__device__ void gram_body(int bid, char* smem,
                          const float* cW1, const float* cW2,
                          const float* fW1, const float* fW2, float* Gall) {
    const float* W; int O, K, wsel, tile;
    if (bid < 64)       { W = cW1; O = 128; K = 576;  wsel = 0; tile = bid; }
    else if (bid < 80)  { W = cW2; O = 64;  K = 1152; wsel = 1; tile = bid - 64; }
    else if (bid < 144) { W = fW1; O = 128; K = 1152; wsel = 2; tile = bid - 80; }
    else                { W = fW2; O = 64;  K = 1152; wsel = 3; tile = bid - 144; }
    int ntiles = O >> 4;
    int ti0 = (tile / ntiles) << 4, tj0 = (tile % ntiles) << 4;
    float (*Wi)[33] = (float(*)[33])smem;
    float (*Wj)[33] = (float(*)[33])(smem + 16 * 33 * 4);
    int tid = threadIdx.x;
    int ti = tid >> 4, tj = tid & 15;
    int r = tid >> 5, c = tid & 31;
    float acc = 0.f;
    for (int k0 = 0; k0 < K; k0 += 32) {
        Wi[r][c]     = W[(size_t)(ti0 + r) * K + k0 + c];
        Wi[r + 8][c] = W[(size_t)(ti0 + r + 8) * K + k0 + c];
        Wj[r][c]     = W[(size_t)(tj0 + r) * K + k0 + c];
        Wj[r + 8][c] = W[(size_t)(tj0 + r + 8) * K + k0 + c];
        __syncthreads();
        #pragma unroll
        for (int k = 0; k < 32; ++k)
            acc += Wi[ti][k] * Wj[tj][k];
        __syncthreads();
    }
    Gall[wsel * 16384 + (ti0 + ti) * 128 + (tj0 + tj)] = acc;
}

// ---- x NCHW f32 -> [pix][64] bf16 (16640B smem) ----
__device__ void convert_body(int bid, char* smem,
                             const float* __restrict__ x, u16* __restrict__ xb) {
    float (*tile)[65] = (float(*)[65])smem;
    int b = bid >> 6, y = bid & 63;
    int tid = threadIdx.x;
    #pragma unroll
    for (int i = 0; i < 16; ++i) {
        int c = (tid >> 6) + i * 4;
        tile[c][tid & 63] = x[(((size_t)b * 64 + c) << 12) + (y << 6) + (tid & 63)];
    }
    __syncthreads();
    #pragma unroll
    for (int i = 0; i < 16; ++i) {
        int idx = tid + i * 256;
        int p = idx >> 6, c = idx & 63;
        xb[(((size_t)b << 12) + (y << 6) + p) * 64 + c] = f2bf(tile[c][p]);
    }
}

// ---- projection weight/bias prep ----
__device__ void prep_proj_body(int bid,
               const float* q1W, const float* k1W, const float* v1W, const float* s1W,
               const float* q2W, const float* k2W, const float* v2W, const float* s2W,
               const float* q1b, const float* k1b, const float* v1b, const float* s1b,
               const float* q2b, const float* k2b, const float* v2b, const float* s2b,
               u16* wp1, u16* wp2, float* b1, float* b2) {
    const float* W1[4] = {q1W, k1W, v1W, s1W};
    const float* W2[4] = {q2W, k2W, v2W, s2W};
    const float* Bb1[4] = {q1b, k1b, v1b, s1b};
    const float* Bb2[4] = {q2b, k2b, v2b, s2b};
    int idx = bid * 256 + threadIdx.x;
    if (idx < 32768) {
        int w = idx >> 13, r = idx & 8191;
        wp1[(size_t)w * 8192 + r] = f2bf(W1[w][r]);
    } else if (idx < 65536) {
        int j = idx - 32768; int w = j >> 13, r = j & 8191;
        wp2[(size_t)w * 8192 + r] = f2bf(W2[w][r]);
    } else if (idx < 66048) {
        int j = idx - 65536; int w = j >> 7; b1[j] = Bb1[w][j & 127];
    } else if (idx < 66304) {
        int j = idx - 66048; int w = j >> 6; b2[j] = Bb2[w][j & 63];
    }
}

// ---- conv weight prep ----
__device__ void prep_conv_w_body(int bx, int wsel,
                 const float* __restrict__ cW1, const float* __restrict__ cW2,
                 const float* __restrict__ fW1, const float* __restrict__ fW2,
                 const float* __restrict__ sig,
                 u16* wc1, u16* wc2, u16* wf1, u16* wf2) {
    const float* src; u16* dst; int O, C;
    switch (wsel) {
        case 0:  src = cW1; dst = wc1; O = 128; C = 64;  break;
        case 1:  src = cW2; dst = wc2; O = 64;  C = 128; break;
        case 2:  src = fW1; dst = wf1; O = 128; C = 128; break;
        default: src = fW2; dst = wf2; O = 64;  C = 128; break;
    }
    int idx = bx * 256 + threadIdx.x;
    if (idx >= O * C * 9) return;
    int o = idx / (C * 9);
    int rem = idx - o * (C * 9);
    int ci = rem / 9, tap = rem - ci * 9;
    float v = src[idx] / sig[wsel];
    dst[(size_t)o * (C * 9) + tap * C + ci] = f2bf(v);
}

// ---- bf16 MFMA GEMM, implicit im2col, BK=CC (rd12 structure) ----
template<int TAPS, int CC, int BN, int OUTM>
__device__ void mm_body(int bx, int by, char* smem,
               const u16* __restrict__ A, const u16* __restrict__ Bw,
               const float* __restrict__ bias, void* __restrict__ Cout,
               int ostride, int ocol0, int do_gelu) {
    constexpr int K = CC * TAPS;
    constexpr int NSTEP = TAPS;
    constexpr int NCH = CC / 8;
    constexpr int NKS = CC / 32;
    constexpr int NF = BN / 32;
    constexpr int HN = BN / 2;
    constexpr int RSTEP = 256 / NCH;
    constexpr int ALD = 128 / RSTEP;
    constexpr int BLD = BN / RSTEP;
    u16* Als = (u16*)smem;
    u16* Bls = (u16*)smem + 128 * CC;
    const int tid = threadIdx.x;
    const int w = tid >> 6;
    const int lane = tid & 63;
    const int m0 = bx * 128;
    const int nt0 = by * BN;
    const int wm = w >> 1, wn = w & 1;

    const int srow = tid / NCH;
    const int sslot = tid % NCH;
    const int csrc = ((sslot ^ (srow & (NCH - 1))) << 3);
    const u16* Bbase = Bw + (size_t)(nt0 + srow) * K + csrc;

    int offA[NKS][4], offB[NKS][NF];
    #pragma unroll
    for (int ks = 0; ks < NKS; ++ks) {
        #pragma unroll
        for (int mf = 0; mf < 4; ++mf) {
            int R = wm * 64 + mf * 16 + (lane & 15);
            int slot = (ks * 4 + (lane >> 4)) ^ (R & (NCH - 1));
            offA[ks][mf] = R * CC + slot * 8;
        }
        #pragma unroll
        for (int nf = 0; nf < NF; ++nf) {
            int Rb = wn * HN + nf * 16 + (lane & 15);
            int slot = (ks * 4 + (lane >> 4)) ^ (Rb & (NCH - 1));
            offB[ks][nf] = Rb * CC + slot * 8;
        }
    }

    f32x4 acc[4][NF];
    #pragma unroll
    for (int i = 0; i < 4; ++i)
        #pragma unroll
        for (int j = 0; j < NF; ++j) {
            f32x4 z = {0.f, 0.f, 0.f, 0.f};
            acc[i][j] = z;
        }

    #pragma unroll
    for (int kt = 0; kt < NSTEP; ++kt) {
        const int kk = kt * CC;
        const int dy = (TAPS == 9) ? (kt / 3 - 1) : 0;
        const int dx = (TAPS == 9) ? (kt % 3 - 1) : 0;
        #pragma unroll
        for (int i = 0; i < ALD; ++i) {
            const int m = m0 + srow + i * RSTEP;
            const u16* ga;
            if constexpr (TAPS == 9) {
                int yy = ((m >> 6) & 63) + dy; yy = min(max(yy, 0), 63);
                int xx = (m & 63) + dx;        xx = min(max(xx, 0), 63);
                ga = A + (size_t)((m & ~4095) | (yy << 6) | xx) * CC + csrc;
            } else {
                ga = A + (size_t)m * CC + csrc;
            }
            g2l16(ga, &Als[(srow + i * RSTEP) * CC + sslot * 8]);
        }
        #pragma unroll
        for (int i = 0; i < BLD; ++i)
            g2l16(Bbase + (size_t)i * RSTEP * K + kk,
                  &Bls[(srow + i * RSTEP) * CC + sslot * 8]);

        __syncthreads();

        #pragma unroll
        for (int ks = 0; ks < NKS; ++ks) {
            bf16x8 af[4];
            #pragma unroll
            for (int mf = 0; mf < 4; ++mf)
                af[mf] = *reinterpret_cast<const bf16x8*>(&Als[offA[ks][mf]]);
            #pragma unroll
            for (int nf = 0; nf < NF; ++nf) {
                bf16x8 bfv = *reinterpret_cast<const bf16x8*>(&Bls[offB[ks][nf]]);
                #pragma unroll
                for (int mf = 0; mf < 4; ++mf)
                    acc[mf][nf] = __builtin_amdgcn_mfma_f32_16x16x32_bf16(
                        af[mf], bfv, acc[mf][nf], 0, 0, 0);
            }
        }
        if (kt + 1 < NSTEP) __syncthreads();
    }

    #pragma unroll
    for (int mf = 0; mf < 4; ++mf) {
        int mrow = m0 + wm * 64 + mf * 16 + (lane >> 4) * 4;
        #pragma unroll
        for (int nf = 0; nf < NF; ++nf) {
            int col = nt0 + wn * HN + nf * 16 + (lane & 15);
            float bv = bias[col];
            if (OUTM == 0) {
                u16* Co = (u16*)Cout;
                #pragma unroll
                for (int j = 0; j < 4; ++j) {
                    float v = acc[mf][nf][j] + bv;
                    if (do_gelu) v = gelu_f(v);
                    Co[(size_t)(mrow + j) * ostride + ocol0 + col] = f2bf(v);
                }
            } else {
                float* Co = (float*)Cout;
                int b = m0 >> 12;
                int pixb = (mrow & 4095);
                f32x4 vv;
                #pragma unroll
                for (int j = 0; j < 4; ++j)
                    vv[j] = gelu_f(acc[mf][nf][j] + bv);
                *reinterpret_cast<f32x4*>(&Co[((size_t)(b * 64 + col)) * 4096 + pixb]) = vv;
            }
        }
    }
}

// ---- projection GEMM with N-group loop: A staged ONCE, B per group ----
template<int CC, int BN, int NGRP>
__device__ void proj_body(int bx, char* smem,
               const u16* __restrict__ A, const u16* __restrict__ Bw,
               const float* __restrict__ bias, u16* __restrict__ Cout,
               int ostride) {
    constexpr int NCH = CC / 8;
    constexpr int NKS = CC / 32;
    constexpr int NF = BN / 32;
    constexpr int HN = BN / 2;
    constexpr int RSTEP = 256 / NCH;
    constexpr int ALD = 128 / RSTEP;
    constexpr int BLD = BN / RSTEP;
    u16* Als = (u16*)smem;
    u16* Bls = (u16*)smem + 128 * CC;
    const int tid = threadIdx.x;
    const int w = tid >> 6;
    const int lane = tid & 63;
    const int m0 = bx * 128;
    const int wm = w >> 1, wn = w & 1;

    const int srow = tid / NCH;
    const int sslot = tid % NCH;
    const int csrc = ((sslot ^ (srow & (NCH - 1))) << 3);

    // ---- stage A once ----
    #pragma unroll
    for (int i = 0; i < ALD; ++i) {
        const int m = m0 + srow + i * RSTEP;
        g2l16(A + (size_t)m * CC + csrc,
              &Als[(srow + i * RSTEP) * CC + sslot * 8]);
    }

    int offA[NKS][4], offB[NKS][NF];
    #pragma unroll
    for (int ks = 0; ks < NKS; ++ks) {
        #pragma unroll
        for (int mf = 0; mf < 4; ++mf) {
            int R = wm * 64 + mf * 16 + (lane & 15);
            int slot = (ks * 4 + (lane >> 4)) ^ (R & (NCH - 1));
            offA[ks][mf] = R * CC + slot * 8;
        }
        #pragma unroll
        for (int nf = 0; nf < NF; ++nf) {
            int Rb = wn * HN + nf * 16 + (lane & 15);
            int slot = (ks * 4 + (lane >> 4)) ^ (Rb & (NCH - 1));
            offB[ks][nf] = Rb * CC + slot * 8;
        }
    }

    #pragma unroll
    for (int g = 0; g < NGRP; ++g) {
        const u16* Bbase = Bw + (size_t)(g * BN + srow) * CC + csrc;
        #pragma unroll
        for (int i = 0; i < BLD; ++i)
            g2l16(Bbase + (size_t)i * RSTEP * CC,
                  &Bls[(srow + i * RSTEP) * CC + sslot * 8]);
        __syncthreads();                 // A(first pass)+B visible

        f32x4 acc[4][NF];
        #pragma unroll
        for (int i = 0; i < 4; ++i)
            #pragma unroll
            for (int j = 0; j < NF; ++j) {
                f32x4 z = {0.f, 0.f, 0.f, 0.f};
                acc[i][j] = z;
            }
        #pragma unroll
        for (int ks = 0; ks < NKS; ++ks) {
            bf16x8 af[4];
            #pragma unroll
            for (int mf = 0; mf < 4; ++mf)
                af[mf] = *reinterpret_cast<const bf16x8*>(&Als[offA[ks][mf]]);
            #pragma unroll
            for (int nf = 0; nf < NF; ++nf) {
                bf16x8 bfv = *reinterpret_cast<const bf16x8*>(&Bls[offB[ks][nf]]);
                #pragma unroll
                for (int mf = 0; mf < 4; ++mf)
                    acc[mf][nf] = __builtin_amdgcn_mfma_f32_16x16x32_bf16(
                        af[mf], bfv, acc[mf][nf], 0, 0, 0);
            }
        }
        #pragma unroll
        for (int mf = 0; mf < 4; ++mf) {
            int mrow = m0 + wm * 64 + mf * 16 + (lane >> 4) * 4;
            #pragma unroll
            for (int nf = 0; nf < NF; ++nf) {
                int col = g * BN + wn * HN + nf * 16 + (lane & 15);
                float bv = bias[col];
                #pragma unroll
                for (int j = 0; j < 4; ++j)
                    Cout[(size_t)(mrow + j) * ostride + col] =
                        f2bf(acc[mf][nf][j] + bv);
            }
        }
        if (g + 1 < NGRP) __syncthreads();   // B readers done before overwrite
    }
}

// ---- attention layer 1: LDS-staged K/V halo (27648B smem) ----
// Block = 16 nodes of one image row; halo = 3 rows x 18 cols, K rows 0..53,
// V rows 54..107, each row 128 u16 (256B). Staged via 27 wave-uniform 1KB
// global_load_lds sweeps (per-lane clamped source); all 9 edges read LDS.
__device__ void attn1_body(int bid, char* smem, const u16* __restrict__ qkvs,
                           u16* __restrict__ h) {
    u16* KV = (u16*)smem;
    const int tid = threadIdx.x;
    const int w = tid >> 6;
    const int lane = tid & 63;
    const int n0 = bid * 16;
    const int imgb = n0 & ~4095;
    const int y = (n0 >> 6) & 63;
    const int x0 = n0 & 63;

    for (int t = w; t < 27; t += 4) {
        const int r = 4 * t + (lane >> 4);
        const int isV = r >= 54;
        const int rr = isV ? r - 54 : r;
        const int ry = rr / 18, rx = rr - ry * 18;
        const int yy = min(max(y + ry - 1, 0), 63);
        const int xx = min(max(x0 - 1 + rx, 0), 63);
        const u16* g = qkvs + (size_t)(imgb + (yy << 6) + xx) * 512
                        + (isV ? 256 : 128) + (lane & 15) * 8;
        g2l16(g, KV + t * 512);
    }
    __syncthreads();

    const int l16 = tid & 15;
    const int nn = tid >> 4;
    const int n = n0 + nn;
    const int x = x0 + nn;
    const u32* qk = (const u32*)qkvs;
    const int nbase = (n << 8) + l16 * 4;
    const u32* Kl = (const u32*)KV;           // row stride 64 u32

    u32x4 qp = *(const u32x4*)(qk + nbase);
    float q[8];
    #pragma unroll
    for (int i = 0; i < 4; ++i) { q[2*i] = blo(qp[i]); q[2*i+1] = bhi(qp[i]); }

    float al[9];
    float mx = -1e30f;
    #pragma unroll
    for (int e = 0; e < 9; ++e) {
        const int dy = e / 3 - 1, dx = e % 3 - 1;
        const bool valid = (unsigned)(y + dy) < 64u && (unsigned)(x + dx) < 64u;
        const int rk = (dy + 1) * 18 + nn + dx + 1;
        u32x4 kp = *(const u32x4*)(Kl + rk * 64 + l16 * 4);
        float p = 0.f;
        #pragma unroll
        for (int i = 0; i < 4; ++i) {
            p = fmaf(q[2*i],   blo(kp[i]), p);
            p = fmaf(q[2*i+1], bhi(kp[i]), p);
        }
        p += __shfl_xor(p, 1);
        al[e] = valid ? p * 0.25f : -1e30f;
        mx = fmaxf(mx, al[e]);
    }
    float s = 0.f;
    #pragma unroll
    for (int e = 0; e < 9; ++e) { al[e] = __expf(al[e] - mx); s += al[e]; }

    float o[8] = {0.f, 0.f, 0.f, 0.f, 0.f, 0.f, 0.f, 0.f};
    #pragma unroll
    for (int e = 0; e < 9; ++e) {
        const int dy = e / 3 - 1, dx = e % 3 - 1;
        const int rk = (dy + 1) * 18 + nn + dx + 1;
        u32x4 vp = *(const u32x4*)(Kl + (54 + rk) * 64 + l16 * 4);
        const float a = al[e];
        #pragma unroll
        for (int i = 0; i < 4; ++i) {
            o[2*i]   = fmaf(a, blo(vp[i]), o[2*i]);
            o[2*i+1] = fmaf(a, bhi(vp[i]), o[2*i+1]);
        }
    }
    const float r = __fdividef(1.0f, s + 1e-16f);
    u32x4 sp = *(const u32x4*)(qk + nbase + 192);
    u32x4 res;
    #pragma unroll
    for (int i = 0; i < 4; ++i) {
        float h0 = gelu_f(fmaf(o[2*i],   r, blo(sp[i])));
        float h1 = gelu_f(fmaf(o[2*i+1], r, bhi(sp[i])));
        res[i] = packbf(h0, h1);
    }
    *(u32x4*)((u32*)h + (n << 6) + l16 * 4) = res;
}

// ================= global wrappers =================

__global__ __launch_bounds__(256)
void power_kernel(const float* __restrict__ Gall, float* __restrict__ sig) {
    int wsel = blockIdx.x;
    const float* G = Gall + wsel * 16384;
    const int O = (wsel == 0 || wsel == 2) ? 128 : 64;
    __shared__ float u[128], t[128], red[4];
    int tid = threadIdx.x;
    if (tid < O) u[tid] = 1.0f / sqrtf((float)O);
    __syncthreads();
    for (int it = 0; it < 3; ++it) {
        if (tid < O) {
            float s = 0.f;
            const float4* gr = reinterpret_cast<const float4*>(G + (size_t)tid * 128);
            for (int j = 0; j < O / 4; ++j) {
                float4 g = gr[j];
                s += g.x * u[4*j] + g.y * u[4*j+1] + g.z * u[4*j+2] + g.w * u[4*j+3];
            }
            t[tid] = s;
        }
        __syncthreads();
        float loc = (tid < O) ? t[tid] * t[tid] : 0.f;
        float nt = sqrtf(block_sum(loc, red));
        if (it == 2) {
            float locd = (tid < O) ? u[tid] * t[tid] : 0.f;
            float dot = block_sum(locd, red);
            if (tid == 0) sig[wsel] = nt / sqrtf(dot + 1e-24f);
        } else {
            if (tid < O) u[tid] = t[tid] / (nt + 1e-12f);
            __syncthreads();
        }
    }
}

__global__ __launch_bounds__(256)
void attn2_kernel(const u16* __restrict__ qkvs, u16* __restrict__ xc) {
    const int tid = threadIdx.x;
    const int l8 = tid & 7;
    const int n = blockIdx.x * 32 + (tid >> 3);
    const int y = (n >> 6) & 63, x = n & 63;
    const u32* qk = (const u32*)qkvs;
    const int nbase = (n << 7) + l8 * 4;

    u32x4 qp = *(const u32x4*)(qk + nbase);
    float q[8];
    #pragma unroll
    for (int i = 0; i < 4; ++i) { q[2*i] = blo(qp[i]); q[2*i+1] = bhi(qp[i]); }

    float al[9];
    float mx = -1e30f;
    #pragma unroll
    for (int e = 0; e < 9; ++e) {
        const int dy = e / 3 - 1, dx = e % 3 - 1;
        const bool valid = (unsigned)(y + dy) < 64u && (unsigned)(x + dx) < 64u;
        const int off = valid ? ((dy * 64 + dx) << 7) : 0;
        u32x4 kp = *(const u32x4*)(qk + nbase + off + 32);
        float p = 0.f;
        #pragma unroll
        for (int i = 0; i < 4; ++i) {
            p = fmaf(q[2*i],   blo(kp[i]), p);
            p = fmaf(q[2*i+1], bhi(kp[i]), p);
        }
        p += __shfl_xor(p, 1);
        p += __shfl_xor(p, 2);
        p += __shfl_xor(p, 4);
        al[e] = valid ? p * 0.125f : -1e30f;
        mx = fmaxf(mx, al[e]);
    }
    float s = 0.f;
    #pragma unroll
    for (int e = 0; e < 9; ++e) { al[e] = __expf(al[e] - mx); s += al[e]; }

    float o[8] = {0.f, 0.f, 0.f, 0.f, 0.f, 0.f, 0.f, 0.f};
    #pragma unroll
    for (int e = 0; e < 9; ++e) {
        const int dy = e / 3 - 1, dx = e % 3 - 1;
        const bool valid = (unsigned)(y + dy) < 64u && (unsigned)(x + dx) < 64u;
        const int off = valid ? ((dy * 64 + dx) << 7) : 0;
        u32x4 vp = *(const u32x4*)(qk + nbase + off + 64);
        const float a = al[e];
        #pragma unroll
        for (int i = 0; i < 4; ++i) {
            o[2*i]   = fmaf(a, blo(vp[i]), o[2*i]);
            o[2*i+1] = fmaf(a, bhi(vp[i]), o[2*i+1]);
        }
    }
    const float r = __fdividef(1.0f, s + 1e-16f);
    u32x4 sp = *(const u32x4*)(qk + nbase + 96);
    u32x4 res;
    #pragma unroll
    for (int i = 0; i < 4; ++i) {
        float h0 = gelu_f(fmaf(o[2*i],   r, blo(sp[i])));
        float h1 = gelu_f(fmaf(o[2*i+1], r, bhi(sp[i])));
        res[i] = packbf(h0, h1);
    }
    *(u32x4*)((u32*)xc + (n << 6) + 32 + l8 * 4) = res;
}

template<int TAPS, int CC, int BN, int OUTM>
__global__ __launch_bounds__(256)
void mm_kernel(const u16* __restrict__ A, const u16* __restrict__ Bw,
               const float* __restrict__ bias, void* __restrict__ Cout,
               int ostride, int ocol0, int do_gelu) {
    __shared__ __align__(16) char smem[(128 * CC + BN * CC) * 2];
    mm_body<TAPS, CC, BN, OUTM>(blockIdx.x, blockIdx.y, smem, A, Bw, bias, Cout,
                                ostride, ocol0, do_gelu);
}

// D0: convert_x (1024) || gram (160) || prep_proj (260)
__global__ __launch_bounds__(256)
void fuse_misc(const float* cW1, const float* cW2, const float* fW1,
               const float* fW2, float* Gall,
               const float* x, u16* xb,
               const float* q1W, const float* k1W, const float* v1W, const float* s1W,
               const float* q2W, const float* k2W, const float* v2W, const float* s2W,
               const float* q1b, const float* k1b, const float* v1b, const float* s1b,
               const float* q2b, const float* k2b, const float* v2b, const float* s2b,
               u16* wp1, u16* wp2, float* b1, float* b2) {
    __shared__ __align__(16) char smem[16640];
    int bid = blockIdx.x;
    if (bid < 1024)       convert_body(bid, smem, x, xb);
    else if (bid < 1184)  gram_body(bid - 1024, smem, cW1, cW2, fW1, fW2, Gall);
    else                  prep_proj_body(bid - 1184, q1W, k1W, v1W, s1W,
                                         q2W, k2W, v2W, s2W, q1b, k1b, v1b, s1b,
                                         q2b, k2b, v2b, s2b, wp1, wp2, b1, b2);
}

// D2: proj1 (512, A staged once, 4 N-groups) || prep_conv_w (2304)
__global__ __launch_bounds__(256)
void fuse_p1_w(const u16* xb, const u16* wp1, const float* b1, u16* qkvs1,
               const float* cW1, const float* cW2, const float* fW1,
               const float* fW2, const float* sig,
               u16* wc1, u16* wc2, u16* wf1, u16* wf2) {
    __shared__ __align__(16) char smem[(128 * 64 + 128 * 64) * 2];
    int bid = blockIdx.x;
    if (bid < 512)
        proj_body<64, 128, 4>(bid, smem, xb, wp1, b1, qkvs1, 512);
    else {
        int wk = bid - 512;
        prep_conv_w_body(wk % 576, wk / 576, cW1, cW2, fW1, fW2, sig,
                         wc1, wc2, wf1, wf2);
    }
}

// D3: conv1 (512, writes y1 in d_out) || attn1 (4096, LDS K/V halo)
__global__ __launch_bounds__(256)
void fuse_c1_a1(const u16* xb, const u16* wc1, const float* cb1, u16* y1,
                const u16* qkvs1, u16* hbuf) {
    __shared__ __align__(16) char smem[(128 * 64 + 128 * 64) * 2];
    int bid = blockIdx.x;
    if (bid < 512)
        mm_body<9, 64, 128, 0>(bid, 0, smem, xb, wc1, cb1, (void*)y1, 128, 0, 1);
    else
        attn1_body(bid - 512, smem, qkvs1, hbuf);
}

// D4: conv2 (512, reads y1 in d_out) || proj2 (512, 2 N-groups)
__global__ __launch_bounds__(256)
void fuse_c2_p2(const u16* y1, const u16* wc2, const float* cb2, u16* xc,
                const u16* hbuf, const u16* wp2, const float* b2, u16* qkvs2) {
    __shared__ __align__(16) char smem[(128 * 128 + 128 * 128) * 2];
    int bid = blockIdx.x;
    if (bid < 512)
        mm_body<9, 128, 64, 0>(bid, 0, smem, y1, wc2, cb2, (void*)xc, 128, 0, 1);
    else
        proj_body<128, 128, 2>(bid - 512, smem, hbuf, wp2, b2, qkvs2, 256);
}

// ---------------- host launcher ----------------
extern "C" void kernel_launch(void* const* d_in, const int* in_sizes, int n_in,
                              void* d_out, int out_size, void* d_ws, size_t ws_size,
                              hipStream_t stream) {
    const float* x   = (const float*)d_in[0];
    const float* cW1 = (const float*)d_in[1];
    const float* cb1 = (const float*)d_in[2];
    const float* cW2 = (const float*)d_in[3];
    const float* cb2 = (const float*)d_in[4];
    const float* q1W = (const float*)d_in[5];
    const float* q1b = (const float*)d_in[6];
    const float* k1W = (const float*)d_in[7];
    const float* k1b = (const float*)d_in[8];
    const float* v1W = (const float*)d_in[9];
    const float* v1b = (const float*)d_in[10];
    const float* s1W = (const float*)d_in[11];
    const float* s1b = (const float*)d_in[12];
    const float* q2W = (const float*)d_in[13];
    const float* q2b = (const float*)d_in[14];
    const float* k2W = (const float*)d_in[15];
    const float* k2b = (const float*)d_in[16];
    const float* v2W = (const float*)d_in[17];
    const float* v2b = (const float*)d_in[18];
    const float* s2W = (const float*)d_in[19];
    const float* s2b = (const float*)d_in[20];
    const float* fW1 = (const float*)d_in[21];
    const float* fb1 = (const float*)d_in[22];
    const float* fW2 = (const float*)d_in[23];
    const float* fb2 = (const float*)d_in[24];

    char* ws = (char*)d_ws;
    float* sig  = (float*)(ws + SIG);
    float* b1   = (float*)(ws + B1OFF);
    float* b2   = (float*)(ws + B2OFF);
    u16* wc1    = (u16*)(ws + WC1);
    u16* wc2    = (u16*)(ws + WC2);
    u16* wf1    = (u16*)(ws + WF1);
    u16* wf2    = (u16*)(ws + WF2);
    u16* wp1    = (u16*)(ws + WP1);
    u16* wp2    = (u16*)(ws + WP2);
    u16* xb     = (u16*)(ws + XB);
    u16* hbuf   = (u16*)(ws + HBUF);
    u16* qkvs2  = (u16*)(ws + QKVS2);
    u16* xc     = (u16*)(ws + XC);
    u16* qkvs1  = (u16*)(ws + QKVS1);
    u16* tbuf   = (u16*)(ws + TBUF);
    float* gram = (float*)(ws + GRAM);
    float* out  = (float*)d_out;
    u16* y1     = (u16*)d_out;   // y1 scratch: dead until conv4 rewrites out

    // D0: convert_x || gram || prep_proj
    fuse_misc<<<1444, 256, 0, stream>>>(cW1, cW2, fW1, fW2, gram, x, xb,
        q1W, k1W, v1W, s1W, q2W, k2W, v2W, s2W,
        q1b, k1b, v1b, s1b, q2b, k2b, v2b, s2b, wp1, wp2, b1, b2);
    // D1: power iteration
    power_kernel<<<4, 256, 0, stream>>>(gram, sig);
    // D2: proj1 || prep_conv_w
    fuse_p1_w<<<2816, 256, 0, stream>>>(xb, wp1, b1, qkvs1,
        cW1, cW2, fW1, fW2, sig, wc1, wc2, wf1, wf2);
    // D3: conv1 (-> y1 in d_out) || attn1
    fuse_c1_a1<<<4608, 256, 0, stream>>>(xb, wc1, cb1, y1, qkvs1, hbuf);
    // D4: conv2 || proj2
    fuse_c2_p2<<<1024, 256, 0, stream>>>(y1, wc2, cb2, xc, hbuf, wp2, b2, qkvs2);
    // D5: attn2 -> xc cols 64..127
    attn2_kernel<<<NPIX / 32, 256, 0, stream>>>(qkvs2, xc);
    // D6: conv3 (tbuf aliases dead qkvs1)
    mm_kernel<9, 128, 128, 0><<<dim3(512, 1), 256, 0, stream>>>(
        xc, wf1, fb1, tbuf, 128, 0, 1);
    // D7: conv4 (rewrites every element of d_out)
    mm_kernel<9, 128, 64, 1><<<dim3(512, 1), 256, 0, stream>>>(
        tbuf, wf2, fb2, out, 0, 0, 1);
}

// Round 17
// 188.466 us; speedup vs baseline: 1.1213x; 1.0028x over previous
//
#include <hip/hip_runtime.h>
#include <hip/hip_bf16.h>

typedef unsigned int  u32;
typedef unsigned short u16;
typedef __attribute__((ext_vector_type(8))) short bf16x8;
typedef __attribute__((ext_vector_type(4))) float f32x4;
typedef __attribute__((ext_vector_type(4))) u32 u32x4;

#define NPIX 65536

// ---------------- ws byte offsets ----------------
constexpr size_t SIG   = 0;
constexpr size_t B1OFF = 256;
constexpr size_t B2OFF = B1OFF + 2048;
constexpr size_t WC1   = B2OFF + 1024;        // 128x576 bf16
constexpr size_t WC2   = WC1 + 147456;        // 64x1152
constexpr size_t WF1   = WC2 + 147456;        // 128x1152
constexpr size_t WF2   = WF1 + 294912;        // 64x1152
constexpr size_t WP1   = WF2 + 147456;        // 512x64
constexpr size_t WP2   = WP1 + 65536;         // 256x128
constexpr size_t XB    = WP2 + 65536;         // 65536x64 bf16
constexpr size_t HBUF  = XB + 8388608;        // 65536x128 bf16
constexpr size_t QKVS2 = HBUF + 16777216;     // 65536x256 bf16
constexpr size_t XC    = QKVS2 + 33554432;    // 65536x128 bf16 concat
constexpr size_t QKVS1 = XC + 16777216;       // 65536x512 bf16
constexpr size_t TBUF  = QKVS1 + 16777216;    // alias into dead qkvs1 (D6 only)
constexpr size_t GRAM  = QKVS1 + 67108864;
// y1 (conv1 out) lives in d_out (dead until conv4 rewrites every element).

// ---------------- helpers ----------------
__device__ __forceinline__ float gelu_f(float v) {
    float xa = fabsf(v) * 0.70710678118654752f;
    float t  = __fdividef(1.0f, fmaf(0.3275911f, xa, 1.0f));
    float poly = t * fmaf(t, fmaf(t, fmaf(t, fmaf(t, 1.061405429f, -1.453152027f),
                   1.421413741f), -0.284496736f), 0.254829592f);
    float erfv = 1.0f - poly * __expf(-xa * xa);
    erfv = copysignf(erfv, v);
    return 0.5f * v * (1.0f + erfv);
}
__device__ __forceinline__ u16 f2bf(float f) {
    __hip_bfloat16 b = __float2bfloat16(f);
    return *reinterpret_cast<u16*>(&b);
}
__device__ __forceinline__ float blo(u32 u) {
    union { u32 i; float f; } x; x.i = u << 16; return x.f;
}
__device__ __forceinline__ float bhi(u32 u) {
    union { u32 i; float f; } x; x.i = u & 0xffff0000u; return x.f;
}
__device__ __forceinline__ u32 packbf(float a, float b) {
    return (u32)f2bf(a) | ((u32)f2bf(b) << 16);
}
__device__ __forceinline__ void g2l16(const void* g, void* l) {
    __builtin_amdgcn_global_load_lds(
        (const __attribute__((address_space(1))) u32*)g,
        (__attribute__((address_space(3))) u32*)l, 16, 0, 0);
}

// ---------------- block reduction ----------------
__device__ float block_sum(float vv, float* red) {
    #pragma unroll
    for (int m = 1; m < 64; m <<= 1) vv += __shfl_xor(vv, m);
    int tid = threadIdx.x;
    __syncthreads();
    if ((tid & 63) == 0) red[tid >> 6] = vv;
    __syncthreads();
    return red[0] + red[1] + red[2] + red[3];
}

// ================= device bodies =================

// ---- Gram tile (4224B smem) ----
__device__ void gram_body(int bid, char* smem,
                          const float* cW1, const float* cW2,
                          const float* fW1, const float* fW2, float* Gall) {
    const float* W; int O, K, wsel, tile;
    if (bid < 64)       { W = cW1; O = 128; K = 576;  wsel = 0; tile = bid; }
    else if (bid < 80)  { W = cW2; O = 64;  K = 1152; wsel = 1; tile = bid - 64; }
    else if (bid < 144) { W = fW1; O = 128; K = 1152; wsel = 2; tile = bid - 80; }
    else                { W = fW2; O = 64;  K = 1152; wsel = 3; tile = bid - 144; }
    int ntiles = O >> 4;
    int ti0 = (tile / ntiles) << 4, tj0 = (tile % ntiles) << 4;
    float (*Wi)[33] = (float(*)[33])smem;
    float (*Wj)[33] = (float(*)[33])(smem + 16 * 33 * 4);
    int tid = threadIdx.x;
    int ti = tid >> 4, tj = tid & 15;
    int r = tid >> 5, c = tid & 31;
    float acc = 0.f;
    for (int k0 = 0; k0 < K; k0 += 32) {
        Wi[r][c]     = W[(size_t)(ti0 + r) * K + k0 + c];
        Wi[r + 8][c] = W[(size_t)(ti0 + r + 8) * K + k0 + c];
        Wj[r][c]     = W[(size_t)(tj0 + r) * K + k0 + c];
        Wj[r + 8][c] = W[(size_t)(tj0 + r + 8) * K + k0 + c];
        __syncthreads();
        #pragma unroll
        for (int k = 0; k < 32; ++k)
            acc += Wi[ti][k] * Wj[tj][k];
        __syncthreads();
    }
    Gall[wsel * 16384 + (ti0 + ti) * 128 + (tj0 + tj)] = acc;
}

// ---- x NCHW f32 -> [pix][64] bf16 (16640B smem) ----
__device__ void convert_body(int bid, char* smem,
                             const float* __restrict__ x, u16* __restrict__ xb) {
    float (*tile)[65] = (float(*)[65])smem;
    int b = bid >> 6, y = bid & 63;
    int tid = threadIdx.x;
    #pragma unroll
    for (int i = 0; i < 16; ++i) {
        int c = (tid >> 6) + i * 4;
        tile[c][tid & 63] = x[(((size_t)b * 64 + c) << 12) + (y << 6) + (tid & 63)];
    }
    __syncthreads();
    #pragma unroll
    for (int i = 0; i < 16; ++i) {
        int idx = tid + i * 256;
        int p = idx >> 6, c = idx & 63;
        xb[(((size_t)b << 12) + (y << 6) + p) * 64 + c] = f2bf(tile[c][p]);
    }
}

// ---- projection weight/bias prep ----
__device__ void prep_proj_body(int bid,
               const float* q1W, const float* k1W, const float* v1W, const float* s1W,
               const float* q2W, const float* k2W, const float* v2W, const float* s2W,
               const float* q1b, const float* k1b, const float* v1b, const float* s1b,
               const float* q2b, const float* k2b, const float* v2b, const float* s2b,
               u16* wp1, u16* wp2, float* b1, float* b2) {
    const float* W1[4] = {q1W, k1W, v1W, s1W};
    const float* W2[4] = {q2W, k2W, v2W, s2W};
    const float* Bb1[4] = {q1b, k1b, v1b, s1b};
    const float* Bb2[4] = {q2b, k2b, v2b, s2b};
    int idx = bid * 256 + threadIdx.x;
    if (idx < 32768) {
        int w = idx >> 13, r = idx & 8191;
        wp1[(size_t)w * 8192 + r] = f2bf(W1[w][r]);
    } else if (idx < 65536) {
        int j = idx - 32768; int w = j >> 13, r = j & 8191;
        wp2[(size_t)w * 8192 + r] = f2bf(W2[w][r]);
    } else if (idx < 66048) {
        int j = idx - 65536; int w = j >> 7; b1[j] = Bb1[w][j & 127];
    } else if (idx < 66304) {
        int j = idx - 66048; int w = j >> 6; b2[j] = Bb2[w][j & 63];
    }
}

// ---- conv weight prep ----
__device__ void prep_conv_w_body(int bx, int wsel,
                 const float* __restrict__ cW1, const float* __restrict__ cW2,
                 const float* __restrict__ fW1, const float* __restrict__ fW2,
                 const float* __restrict__ sig,
                 u16* wc1, u16* wc2, u16* wf1, u16* wf2) {
    const float* src; u16* dst; int O, C;
    switch (wsel) {
        case 0:  src = cW1; dst = wc1; O = 128; C = 64;  break;
        case 1:  src = cW2; dst = wc2; O = 64;  C = 128; break;
        case 2:  src = fW1; dst = wf1; O = 128; C = 128; break;
        default: src = fW2; dst = wf2; O = 64;  C = 128; break;
    }
    int idx = bx * 256 + threadIdx.x;
    if (idx >= O * C * 9) return;
    int o = idx / (C * 9);
    int rem = idx - o * (C * 9);
    int ci = rem / 9, tap = rem - ci * 9;
    float v = src[idx] / sig[wsel];
    dst[(size_t)o * (C * 9) + tap * C + ci] = f2bf(v);
}

// ---- direct conv, dy-row-reuse: stage 2 clamped rows per dy ONCE, run 3 dx taps ----
// Block = 128 pixels = 2 image rows. A buffer [2][W][CC] (position p stores
// clamp(col p-1) of the dy-shifted clamped row); tap dx reads position col+dx+1.
// B tap slice staged per tap (single-buffered, rd12 discipline). A-staging bytes
// drop 3x vs im2col (9 taps -> 3 dy stages).
template<int CC, int BN, int OUTM>
__device__ void conv_body(int bx, char* smem,
               const u16* __restrict__ A, const u16* __restrict__ Bw,
               const float* __restrict__ bias, void* __restrict__ Cout,
               int ostride, int ocol0, int do_gelu) {
    constexpr int K = CC * 9;
    constexpr int NCH = CC / 8;            // 16B chunks per position
    constexpr int NKS = CC / 32;           // k-slices per tap
    constexpr int NF = BN / 32;
    constexpr int HN = BN / 2;
    constexpr int CPL = 512 / CC;          // positions per 1KB wave load
    constexpr int W = (CC == 64) ? 72 : 68;
    constexpr int NLR = W / CPL;           // wave loads per image row
    constexpr int RSTEP = 256 / NCH;
    constexpr int BLD = BN / RSTEP;
    u16* Ah  = (u16*)smem;                 // [2][W][CC]
    u16* Bls = (u16*)smem + 2 * W * CC;    // [BN][CC]

    const int tid = threadIdx.x;
    const int w = tid >> 6;
    const int lane = tid & 63;
    const int wm = w >> 1, wn = w & 1;
    const int m0 = bx * 128;
    const int img = m0 >> 12;
    const int y0 = (m0 >> 6) & 63;         // rows y0, y0+1
    const int lr = lane & 15, lg = lane >> 4;

    // B staging constants (rd12 scheme)
    const int srowB = tid / NCH;
    const int sslotB = tid % NCH;
    const int csrcB = ((sslotB ^ (srowB & (NCH - 1))) << 3);
    // A staging lane split
    const int apos = lane / NCH;           // position offset within load
    const int achk = lane % NCH;

    // hoisted swizzled B frag offsets
    int offB[NKS][NF];
    #pragma unroll
    for (int ks = 0; ks < NKS; ++ks)
        #pragma unroll
        for (int nf = 0; nf < NF; ++nf) {
            int Rb = wn * HN + nf * 16 + lr;
            int slot = (ks * 4 + lg) ^ (Rb & (NCH - 1));
            offB[ks][nf] = Rb * CC + slot * 8;
        }

    f32x4 acc[4][NF];
    #pragma unroll
    for (int i = 0; i < 4; ++i)
        #pragma unroll
        for (int j = 0; j < NF; ++j) {
            f32x4 z = {0.f, 0.f, 0.f, 0.f};
            acc[i][j] = z;
        }

    #pragma unroll
    for (int d = 0; d < 3; ++d) {          // dy = d-1
        // ---- stage A rows for this dy (clamped y and x) ----
        for (int t0 = 0; t0 < 2 * NLR; t0 += 4) {
            int t = t0 + w;
            if (t < 2 * NLR) {
                int imgrow = t / NLR;
                int pos0 = (t - imgrow * NLR) * CPL;
                int yy = min(max(y0 + imgrow + d - 1, 0), 63);
                int pos = pos0 + apos;
                int xx = min(max(pos - 1, 0), 63);
                int key = (imgrow * W + pos) & (NCH - 1);
                const u16* g = A + (size_t)((img << 12) + (yy << 6) + xx) * CC
                                 + ((achk ^ key) << 3);
                g2l16(g, Ah + (size_t)(imgrow * W + pos0) * CC);
            }
        }
        #pragma unroll
        for (int dxi = 0; dxi < 3; ++dxi) {
            const int tap = d * 3 + dxi;
            // ---- stage B tap slice ----
            #pragma unroll
            for (int i = 0; i < BLD; ++i)
                g2l16(Bw + (size_t)(srowB + i * RSTEP) * K + tap * CC + csrcB,
                      Bls + (size_t)(srowB + i * RSTEP) * CC + sslotB * 8);
            __syncthreads();               // A(dy) + B(tap) visible

            #pragma unroll
            for (int ks = 0; ks < NKS; ++ks) {
                bf16x8 af[4];
                #pragma unroll
                for (int mf = 0; mf < 4; ++mf) {
                    int r = wm * W + mf * 16 + lr + dxi;   // col + dx + 1
                    int addr = r * CC + (((ks * 4 + lg) ^ (r & (NCH - 1))) << 3);
                    af[mf] = *reinterpret_cast<const bf16x8*>(&Ah[addr]);
                }
                #pragma unroll
                for (int nf = 0; nf < NF; ++nf) {
                    bf16x8 bfv = *reinterpret_cast<const bf16x8*>(&Bls[offB[ks][nf]]);
                    #pragma unroll
                    for (int mf = 0; mf < 4; ++mf)
                        acc[mf][nf] = __builtin_amdgcn_mfma_f32_16x16x32_bf16(
                            af[mf], bfv, acc[mf][nf], 0, 0, 0);
                }
            }
            if (tap < 8) __syncthreads();  // readers done before B/A overwrite
        }
    }

    // ---- epilogue (identical mapping to rd12) ----
    #pragma unroll
    for (int mf = 0; mf < 4; ++mf) {
        int mrow = m0 + wm * 64 + mf * 16 + lg * 4;
        #pragma unroll
        for (int nf = 0; nf < NF; ++nf) {
            int col = wn * HN + nf * 16 + lr;
            float bv = bias[col];
            if (OUTM == 0) {
                u16* Co = (u16*)Cout;
                #pragma unroll
                for (int j = 0; j < 4; ++j) {
                    float v = acc[mf][nf][j] + bv;
                    if (do_gelu) v = gelu_f(v);
                    Co[(size_t)(mrow + j) * ostride + ocol0 + col] = f2bf(v);
                }
            } else {
                float* Co = (float*)Cout;
                int b = m0 >> 12;
                int pixb = (mrow & 4095);
                f32x4 vv;
                #pragma unroll
                for (int j = 0; j < 4; ++j)
                    vv[j] = gelu_f(acc[mf][nf][j] + bv);
                *reinterpret_cast<f32x4*>(&Co[((size_t)(b * 64 + col)) * 4096 + pixb]) = vv;
            }
        }
    }
}

// ---- projection GEMM with N-group loop: A staged ONCE, B per group ----
template<int CC, int BN, int NGRP>
__device__ void proj_body(int bx, char* smem,
               const u16* __restrict__ A, const u16* __restrict__ Bw,
               const float* __restrict__ bias, u16* __restrict__ Cout,
               int ostride) {
    constexpr int NCH = CC / 8;
    constexpr int NKS = CC / 32;
    constexpr int NF = BN / 32;
    constexpr int HN = BN / 2;
    constexpr int RSTEP = 256 / NCH;
    constexpr int ALD = 128 / RSTEP;
    constexpr int BLD = BN / RSTEP;
    u16* Als = (u16*)smem;
    u16* Bls = (u16*)smem + 128 * CC;
    const int tid = threadIdx.x;
    const int w = tid >> 6;
    const int lane = tid & 63;
    const int m0 = bx * 128;
    const int wm = w >> 1, wn = w & 1;

    const int srow = tid / NCH;
    const int sslot = tid % NCH;
    const int csrc = ((sslot ^ (srow & (NCH - 1))) << 3);

    #pragma unroll
    for (int i = 0; i < ALD; ++i) {
        const int m = m0 + srow + i * RSTEP;
        g2l16(A + (size_t)m * CC + csrc,
              &Als[(srow + i * RSTEP) * CC + sslot * 8]);
    }

    int offA[NKS][4], offB[NKS][NF];
    #pragma unroll
    for (int ks = 0; ks < NKS; ++ks) {
        #pragma unroll
        for (int mf = 0; mf < 4; ++mf) {
            int R = wm * 64 + mf * 16 + (lane & 15);
            int slot = (ks * 4 + (lane >> 4)) ^ (R & (NCH - 1));
            offA[ks][mf] = R * CC + slot * 8;
        }
        #pragma unroll
        for (int nf = 0; nf < NF; ++nf) {
            int Rb = wn * HN + nf * 16 + (lane & 15);
            int slot = (ks * 4 + (lane >> 4)) ^ (Rb & (NCH - 1));
            offB[ks][nf] = Rb * CC + slot * 8;
        }
    }

    #pragma unroll
    for (int g = 0; g < NGRP; ++g) {
        const u16* Bbase = Bw + (size_t)(g * BN + srow) * CC + csrc;
        #pragma unroll
        for (int i = 0; i < BLD; ++i)
            g2l16(Bbase + (size_t)i * RSTEP * CC,
                  &Bls[(srow + i * RSTEP) * CC + sslot * 8]);
        __syncthreads();

        f32x4 acc[4][NF];
        #pragma unroll
        for (int i = 0; i < 4; ++i)
            #pragma unroll
            for (int j = 0; j < NF; ++j) {
                f32x4 z = {0.f, 0.f, 0.f, 0.f};
                acc[i][j] = z;
            }
        #pragma unroll
        for (int ks = 0; ks < NKS; ++ks) {
            bf16x8 af[4];
            #pragma unroll
            for (int mf = 0; mf < 4; ++mf)
                af[mf] = *reinterpret_cast<const bf16x8*>(&Als[offA[ks][mf]]);
            #pragma unroll
            for (int nf = 0; nf < NF; ++nf) {
                bf16x8 bfv = *reinterpret_cast<const bf16x8*>(&Bls[offB[ks][nf]]);
                #pragma unroll
                for (int mf = 0; mf < 4; ++mf)
                    acc[mf][nf] = __builtin_amdgcn_mfma_f32_16x16x32_bf16(
                        af[mf], bfv, acc[mf][nf], 0, 0, 0);
            }
        }
        #pragma unroll
        for (int mf = 0; mf < 4; ++mf) {
            int mrow = m0 + wm * 64 + mf * 16 + (lane >> 4) * 4;
            #pragma unroll
            for (int nf = 0; nf < NF; ++nf) {
                int col = g * BN + wn * HN + nf * 16 + (lane & 15);
                float bv = bias[col];
                #pragma unroll
                for (int j = 0; j < 4; ++j)
                    Cout[(size_t)(mrow + j) * ostride + col] =
                        f2bf(acc[mf][nf][j] + bv);
            }
        }
        if (g + 1 < NGRP) __syncthreads();
    }
}

// ---- attention layer 1: LDS-staged K/V halo (27648B smem) ----
__device__ void attn1_body(int bid, char* smem, const u16* __restrict__ qkvs,
                           u16* __restrict__ h) {
    u16* KV = (u16*)smem;
    const int tid = threadIdx.x;
    const int w = tid >> 6;
    const int lane = tid & 63;
    const int n0 = bid * 16;
    const int imgb = n0 & ~4095;
    const int y = (n0 >> 6) & 63;
    const int x0 = n0 & 63;

    for (int t = w; t < 27; t += 4) {
        const int r = 4 * t + (lane >> 4);
        const int isV = r >= 54;
        const int rr = isV ? r - 54 : r;
        const int ry = rr / 18, rx = rr - ry * 18;
        const int yy = min(max(y + ry - 1, 0), 63);
        const int xx = min(max(x0 - 1 + rx, 0), 63);
        const u16* g = qkvs + (size_t)(imgb + (yy << 6) + xx) * 512
                        + (isV ? 256 : 128) + (lane & 15) * 8;
        g2l16(g, KV + t * 512);
    }
    __syncthreads();

    const int l16 = tid & 15;
    const int nn = tid >> 4;
    const int n = n0 + nn;
    const int x = x0 + nn;
    const u32* qk = (const u32*)qkvs;
    const int nbase = (n << 8) + l16 * 4;
    const u32* Kl = (const u32*)KV;

    u32x4 qp = *(const u32x4*)(qk + nbase);
    float q[8];
    #pragma unroll
    for (int i = 0; i < 4; ++i) { q[2*i] = blo(qp[i]); q[2*i+1] = bhi(qp[i]); }

    float al[9];
    float mx = -1e30f;
    #pragma unroll
    for (int e = 0; e < 9; ++e) {
        const int dy = e / 3 - 1, dx = e % 3 - 1;
        const bool valid = (unsigned)(y + dy) < 64u && (unsigned)(x + dx) < 64u;
        const int rk = (dy + 1) * 18 + nn + dx + 1;
        u32x4 kp = *(const u32x4*)(Kl + rk * 64 + l16 * 4);
        float p = 0.f;
        #pragma unroll
        for (int i = 0; i < 4; ++i) {
            p = fmaf(q[2*i],   blo(kp[i]), p);
            p = fmaf(q[2*i+1], bhi(kp[i]), p);
        }
        p += __shfl_xor(p, 1);
        al[e] = valid ? p * 0.25f : -1e30f;
        mx = fmaxf(mx, al[e]);
    }
    float s = 0.f;
    #pragma unroll
    for (int e = 0; e < 9; ++e) { al[e] = __expf(al[e] - mx); s += al[e]; }

    float o[8] = {0.f, 0.f, 0.f, 0.f, 0.f, 0.f, 0.f, 0.f};
    #pragma unroll
    for (int e = 0; e < 9; ++e) {
        const int dy = e / 3 - 1, dx = e % 3 - 1;
        const int rk = (dy + 1) * 18 + nn + dx + 1;
        u32x4 vp = *(const u32x4*)(Kl + (54 + rk) * 64 + l16 * 4);
        const float a = al[e];
        #pragma unroll
        for (int i = 0; i < 4; ++i) {
            o[2*i]   = fmaf(a, blo(vp[i]), o[2*i]);
            o[2*i+1] = fmaf(a, bhi(vp[i]), o[2*i+1]);
        }
    }
    const float r = __fdividef(1.0f, s + 1e-16f);
    u32x4 sp = *(const u32x4*)(qk + nbase + 192);
    u32x4 res;
    #pragma unroll
    for (int i = 0; i < 4; ++i) {
        float h0 = gelu_f(fmaf(o[2*i],   r, blo(sp[i])));
        float h1 = gelu_f(fmaf(o[2*i+1], r, bhi(sp[i])));
        res[i] = packbf(h0, h1);
    }
    *(u32x4*)((u32*)h + (n << 6) + l16 * 4) = res;
}

// ================= global wrappers =================

__global__ __launch_bounds__(256)
void power_kernel(const float* __restrict__ Gall, float* __restrict__ sig) {
    int wsel = blockIdx.x;
    const float* G = Gall + wsel * 16384;
    const int O = (wsel == 0 || wsel == 2) ? 128 : 64;
    __shared__ float u[128], t[128], red[4];
    int tid = threadIdx.x;
    if (tid < O) u[tid] = 1.0f / sqrtf((float)O);
    __syncthreads();
    for (int it = 0; it < 3; ++it) {
        if (tid < O) {
            float s = 0.f;
            const float4* gr = reinterpret_cast<const float4*>(G + (size_t)tid * 128);
            for (int j = 0; j < O / 4; ++j) {
                float4 g = gr[j];
                s += g.x * u[4*j] + g.y * u[4*j+1] + g.z * u[4*j+2] + g.w * u[4*j+3];
            }
            t[tid] = s;
        }
        __syncthreads();
        float loc = (tid < O) ? t[tid] * t[tid] : 0.f;
        float nt = sqrtf(block_sum(loc, red));
        if (it == 2) {
            float locd = (tid < O) ? u[tid] * t[tid] : 0.f;
            float dot = block_sum(locd, red);
            if (tid == 0) sig[wsel] = nt / sqrtf(dot + 1e-24f);
        } else {
            if (tid < O) u[tid] = t[tid] / (nt + 1e-12f);
            __syncthreads();
        }
    }
}

__global__ __launch_bounds__(256)
void attn2_kernel(const u16* __restrict__ qkvs, u16* __restrict__ xc) {
    const int tid = threadIdx.x;
    const int l8 = tid & 7;
    const int n = blockIdx.x * 32 + (tid >> 3);
    const int y = (n >> 6) & 63, x = n & 63;
    const u32* qk = (const u32*)qkvs;
    const int nbase = (n << 7) + l8 * 4;

    u32x4 qp = *(const u32x4*)(qk + nbase);
    float q[8];
    #pragma unroll
    for (int i = 0; i < 4; ++i) { q[2*i] = blo(qp[i]); q[2*i+1] = bhi(qp[i]); }

    float al[9];
    float mx = -1e30f;
    #pragma unroll
    for (int e = 0; e < 9; ++e) {
        const int dy = e / 3 - 1, dx = e % 3 - 1;
        const bool valid = (unsigned)(y + dy) < 64u && (unsigned)(x + dx) < 64u;
        const int off = valid ? ((dy * 64 + dx) << 7) : 0;
        u32x4 kp = *(const u32x4*)(qk + nbase + off + 32);
        float p = 0.f;
        #pragma unroll
        for (int i = 0; i < 4; ++i) {
            p = fmaf(q[2*i],   blo(kp[i]), p);
            p = fmaf(q[2*i+1], bhi(kp[i]), p);
        }
        p += __shfl_xor(p, 1);
        p += __shfl_xor(p, 2);
        p += __shfl_xor(p, 4);
        al[e] = valid ? p * 0.125f : -1e30f;
        mx = fmaxf(mx, al[e]);
    }
    float s = 0.f;
    #pragma unroll
    for (int e = 0; e < 9; ++e) { al[e] = __expf(al[e] - mx); s += al[e]; }

    float o[8] = {0.f, 0.f, 0.f, 0.f, 0.f, 0.f, 0.f, 0.f};
    #pragma unroll
    for (int e = 0; e < 9; ++e) {
        const int dy = e / 3 - 1, dx = e % 3 - 1;
        const bool valid = (unsigned)(y + dy) < 64u && (unsigned)(x + dx) < 64u;
        const int off = valid ? ((dy * 64 + dx) << 7) : 0;
        u32x4 vp = *(const u32x4*)(qk + nbase + off + 64);
        const float a = al[e];
        #pragma unroll
        for (int i = 0; i < 4; ++i) {
            o[2*i]   = fmaf(a, blo(vp[i]), o[2*i]);
            o[2*i+1] = fmaf(a, bhi(vp[i]), o[2*i+1]);
        }
    }
    const float r = __fdividef(1.0f, s + 1e-16f);
    u32x4 sp = *(const u32x4*)(qk + nbase + 96);
    u32x4 res;
    #pragma unroll
    for (int i = 0; i < 4; ++i) {
        float h0 = gelu_f(fmaf(o[2*i],   r, blo(sp[i])));
        float h1 = gelu_f(fmaf(o[2*i+1], r, bhi(sp[i])));
        res[i] = packbf(h0, h1);
    }
    *(u32x4*)((u32*)xc + (n << 6) + 32 + l8 * 4) = res;
}

// standalone conv wrapper (conv3, conv4)
template<int CC, int BN, int OUTM>
__global__ __launch_bounds__(256)
void conv_kernel(const u16* __restrict__ A, const u16* __restrict__ Bw,
                 const float* __restrict__ bias, void* __restrict__ Cout,
                 int ostride, int ocol0, int do_gelu) {
    constexpr int W = (CC == 64) ? 72 : 68;
    __shared__ __align__(16) char smem[(2 * W * CC + BN * CC) * 2];
    conv_body<CC, BN, OUTM>(blockIdx.x, smem, A, Bw, bias, Cout,
                            ostride, ocol0, do_gelu);
}

// D0: convert_x (1024) || gram (160) || prep_proj (260)
__global__ __launch_bounds__(256)
void fuse_misc(const float* cW1, const float* cW2, const float* fW1,
               const float* fW2, float* Gall,
               const float* x, u16* xb,
               const float* q1W, const float* k1W, const float* v1W, const float* s1W,
               const float* q2W, const float* k2W, const float* v2W, const float* s2W,
               const float* q1b, const float* k1b, const float* v1b, const float* s1b,
               const float* q2b, const float* k2b, const float* v2b, const float* s2b,
               u16* wp1, u16* wp2, float* b1, float* b2) {
    __shared__ __align__(16) char smem[16640];
    int bid = blockIdx.x;
    if (bid < 1024)       convert_body(bid, smem, x, xb);
    else if (bid < 1184)  gram_body(bid - 1024, smem, cW1, cW2, fW1, fW2, Gall);
    else                  prep_proj_body(bid - 1184, q1W, k1W, v1W, s1W,
                                         q2W, k2W, v2W, s2W, q1b, k1b, v1b, s1b,
                                         q2b, k2b, v2b, s2b, wp1, wp2, b1, b2);
}

// D2: proj1 (512, A staged once, 4 N-groups) || prep_conv_w (2304)
__global__ __launch_bounds__(256)
void fuse_p1_w(const u16* xb, const u16* wp1, const float* b1, u16* qkvs1,
               const float* cW1, const float* cW2, const float* fW1,
               const float* fW2, const float* sig,
               u16* wc1, u16* wc2, u16* wf1, u16* wf2) {
    __shared__ __align__(16) char smem[(128 * 64 + 128 * 64) * 2];
    int bid = blockIdx.x;
    if (bid < 512)
        proj_body<64, 128, 4>(bid, smem, xb, wp1, b1, qkvs1, 512);
    else {
        int wk = bid - 512;
        prep_conv_w_body(wk % 576, wk / 576, cW1, cW2, fW1, fW2, sig,
                         wc1, wc2, wf1, wf2);
    }
}

// D3: conv1 (512, dy-reuse, writes y1 in d_out) || attn1 (4096, LDS halo)
__global__ __launch_bounds__(256)
void fuse_c1_a1(const u16* xb, const u16* wc1, const float* cb1, u16* y1,
                const u16* qkvs1, u16* hbuf) {
    __shared__ __align__(16) char smem[(2 * 72 * 64 + 128 * 64) * 2];
    int bid = blockIdx.x;
    if (bid < 512)
        conv_body<64, 128, 0>(bid, smem, xb, wc1, cb1, (void*)y1, 128, 0, 1);
    else
        attn1_body(bid - 512, smem, qkvs1, hbuf);
}

// D4: conv2 (512, dy-reuse) || proj2 (512, 2 N-groups)
__global__ __launch_bounds__(256)
void fuse_c2_p2(const u16* y1, const u16* wc2, const float* cb2, u16* xc,
                const u16* hbuf, const u16* wp2, const float* b2, u16* qkvs2) {
    __shared__ __align__(16) char smem[(128 * 128 + 128 * 128) * 2];
    int bid = blockIdx.x;
    if (bid < 512)
        conv_body<128, 64, 0>(bid, smem, y1, wc2, cb2, (void*)xc, 128, 0, 1);
    else
        proj_body<128, 128, 2>(bid - 512, smem, hbuf, wp2, b2, qkvs2, 256);
}

// ---------------- host launcher ----------------
extern "C" void kernel_launch(void* const* d_in, const int* in_sizes, int n_in,
                              void* d_out, int out_size, void* d_ws, size_t ws_size,
                              hipStream_t stream) {
    const float* x   = (const float*)d_in[0];
    const float* cW1 = (const float*)d_in[1];
    const float* cb1 = (const float*)d_in[2];
    const float* cW2 = (const float*)d_in[3];
    const float* cb2 = (const float*)d_in[4];
    const float* q1W = (const float*)d_in[5];
    const float* q1b = (const float*)d_in[6];
    const float* k1W = (const float*)d_in[7];
    const float* k1b = (const float*)d_in[8];
    const float* v1W = (const float*)d_in[9];
    const float* v1b = (const float*)d_in[10];
    const float* s1W = (const float*)d_in[11];
    const float* s1b = (const float*)d_in[12];
    const float* q2W = (const float*)d_in[13];
    const float* q2b = (const float*)d_in[14];
    const float* k2W = (const float*)d_in[15];
    const float* k2b = (const float*)d_in[16];
    const float* v2W = (const float*)d_in[17];
    const float* v2b = (const float*)d_in[18];
    const float* s2W = (const float*)d_in[19];
    const float* s2b = (const float*)d_in[20];
    const float* fW1 = (const float*)d_in[21];
    const float* fb1 = (const float*)d_in[22];
    const float* fW2 = (const float*)d_in[23];
    const float* fb2 = (const float*)d_in[24];

    char* ws = (char*)d_ws;
    float* sig  = (float*)(ws + SIG);
    float* b1   = (float*)(ws + B1OFF);
    float* b2   = (float*)(ws + B2OFF);
    u16* wc1    = (u16*)(ws + WC1);
    u16* wc2    = (u16*)(ws + WC2);
    u16* wf1    = (u16*)(ws + WF1);
    u16* wf2    = (u16*)(ws + WF2);
    u16* wp1    = (u16*)(ws + WP1);
    u16* wp2    = (u16*)(ws + WP2);
    u16* xb     = (u16*)(ws + XB);
    u16* hbuf   = (u16*)(ws + HBUF);
    u16* qkvs2  = (u16*)(ws + QKVS2);
    u16* xc     = (u16*)(ws + XC);
    u16* qkvs1  = (u16*)(ws + QKVS1);
    u16* tbuf   = (u16*)(ws + TBUF);
    float* gram = (float*)(ws + GRAM);
    float* out  = (float*)d_out;
    u16* y1     = (u16*)d_out;   // y1 scratch: dead until conv4 rewrites out

    // D0: convert_x || gram || prep_proj
    fuse_misc<<<1444, 256, 0, stream>>>(cW1, cW2, fW1, fW2, gram, x, xb,
        q1W, k1W, v1W, s1W, q2W, k2W, v2W, s2W,
        q1b, k1b, v1b, s1b, q2b, k2b, v2b, s2b, wp1, wp2, b1, b2);
    // D1: power iteration
    power_kernel<<<4, 256, 0, stream>>>(gram, sig);
    // D2: proj1 || prep_conv_w
    fuse_p1_w<<<2816, 256, 0, stream>>>(xb, wp1, b1, qkvs1,
        cW1, cW2, fW1, fW2, sig, wc1, wc2, wf1, wf2);
    // D3: conv1 (-> y1 in d_out) || attn1
    fuse_c1_a1<<<4608, 256, 0, stream>>>(xb, wc1, cb1, y1, qkvs1, hbuf);
    // D4: conv2 || proj2
    fuse_c2_p2<<<1024, 256, 0, stream>>>(y1, wc2, cb2, xc, hbuf, wp2, b2, qkvs2);
    // D5: attn2 -> xc cols 64..127
    attn2_kernel<<<NPIX / 32, 256, 0, stream>>>(qkvs2, xc);
    // D6: conv3 (tbuf aliases dead qkvs1)
    conv_kernel<128, 128, 0><<<512, 256, 0, stream>>>(
        xc, wf1, fb1, tbuf, 128, 0, 1);
    // D7: conv4 (rewrites every element of d_out)
    conv_kernel<128, 64, 1><<<512, 256, 0, stream>>>(
        tbuf, wf2, fb2, out, 0, 0, 1);
}